// Round 3
// baseline (327.546 us; speedup 1.0000x reference)
//
#include <hip/hip_runtime.h>
#include <hip/hip_bf16.h>
#include <math.h>

// Problem constants: b=1, D=8, H=128, W=128, C=64; N = 131072 tokens.
// HEADS=4, DIM_HEAD=64, INNER=256.
// Math reformulation:
//   G = X^T X  (64x64)
//   qn2[e] = Wq[:,e]^T G Wq[:,e];  kn2 likewise
//   attn_raw_h = Wk_h^T G Wq_h ;  S = attn_raw * rescale_h / (kn[d]*qn[e])
//   P = softmax_rows(S)
//   W_final = sum_h (Wv_h @ P_h^T) @ Wp_h   (64x64)
//   out = X @ W_final + b_proj + dwconv2(gelu(dwconv1(X)))

#define NTOK 131072

// ---------------- K1: Gram partials ----------------
// 1024 blocks x 256 thr; each block handles 128 tokens; partial[1024][64][64]
__global__ __launch_bounds__(256) void k_gram(const float* __restrict__ x,
                                              float* __restrict__ partial) {
    __shared__ float xs[16][64];
    const int tid = threadIdx.x;
    const int col = tid & 63;
    const int g = tid >> 6;  // 0..3 -> rows g*16..g*16+15
    float acc[16];
#pragma unroll
    for (int i = 0; i < 16; ++i) acc[i] = 0.f;
    const long tok0 = (long)blockIdx.x * 128;
    for (int t0 = 0; t0 < 128; t0 += 16) {
        __syncthreads();
        const float4* src = (const float4*)(x + (tok0 + t0) * 64);
        ((float4*)&xs[0][0])[tid] = src[tid];
        __syncthreads();
#pragma unroll
        for (int t = 0; t < 16; ++t) {
            const float xa = xs[t][col];
#pragma unroll
            for (int j = 0; j < 16; j += 4) {
                const float4 lv = *(const float4*)&xs[t][g * 16 + j];
                acc[j + 0] += lv.x * xa;
                acc[j + 1] += lv.y * xa;
                acc[j + 2] += lv.z * xa;
                acc[j + 3] += lv.w * xa;
            }
        }
    }
    float* p = partial + (size_t)blockIdx.x * 4096;
#pragma unroll
    for (int i = 0; i < 16; ++i) p[(g * 16 + i) * 64 + col] = acc[i];
}

// ---------------- K2: reduce partials -> G (atomic over 16 partial-slices) --
// grid 256: (pslice 0..15) x (eblk 0..15); each thread sums 64 partials for
// one of 256 entries, atomicAdd into G (G pre-zeroed by memset).
__global__ __launch_bounds__(256) void k_reduceG(const float* __restrict__ partial,
                                                 float* __restrict__ G) {
    const int pslice = blockIdx.x >> 4;
    const int eblk = blockIdx.x & 15;
    const int e = eblk * 256 + threadIdx.x;
    const float* p = partial + (size_t)pslice * 64 * 4096 + e;
    float s = 0.f;
#pragma unroll 8
    for (int i = 0; i < 64; ++i) s += p[(size_t)i * 4096];
    atomicAdd(&G[e], s);
}

// ---------------- K3: tiny attention algebra (4 blocks, one per head) ------
__global__ __launch_bounds__(512) void k_attn(const float* __restrict__ G,
                                              const float* __restrict__ w_qkv,
                                              const float* __restrict__ rescale,
                                              const float* __restrict__ w_proj,
                                              float* __restrict__ wf) {
    // LDS layout (floats): Gs(4096)|Bq(4096)|Bk(4096)|Bp(4096)|M1(4096)|M2(4096)|Sb(64x65)
    // PT aliases Gs (Gs dead after phase 1).
    __shared__ float smem[6 * 4096 + 64 * 65];
    float (*Gs)[64] = (float(*)[64])smem;
    float (*PT)[64] = (float(*)[64])smem;  // alias
    float (*Bq)[64] = (float(*)[64])(smem + 4096);    // Wq, later WvT
    float (*Bk)[64] = (float(*)[64])(smem + 8192);    // Wk
    float (*Bp)[64] = (float(*)[64])(smem + 12288);   // Wp
    float (*M1)[64] = (float(*)[64])(smem + 16384);   // G@Wq
    float (*M2)[64] = (float(*)[64])(smem + 20480);   // G@Wk, later ZT
    float (*Sb)[65] = (float(*)[65])(smem + 24576);
    __shared__ float qin[64], kin[64];

    const int h = blockIdx.x;
    const int tid = threadIdx.x;
    const int lane = tid & 63;
    const int g = tid >> 6;      // 0..7
    const int p0 = g * 8;

    // P0: stage G, Wq, Wk, Wp
    for (int idx = tid; idx < 4096; idx += 512) {
        const int a = idx >> 6, e = idx & 63;
        Gs[a][e] = G[idx];
        Bq[a][e] = w_qkv[a * 768 + h * 64 + e];
        Bk[a][e] = w_qkv[a * 768 + 256 + h * 64 + e];
        Bp[a][e] = w_proj[(h * 64 + a) * 64 + e];
    }
    __syncthreads();

    // P1: M1 = G@Wq, M2 = G@Wk (G symmetric: Gs[a][p] == G[p][a])
    {
        float acc[8];
#pragma unroll
        for (int i = 0; i < 8; ++i) acc[i] = 0.f;
        for (int a = 0; a < 64; ++a) {
            const float r = Bq[a][lane];
            const float4 l0 = *(const float4*)&Gs[a][p0];
            const float4 l1 = *(const float4*)&Gs[a][p0 + 4];
            acc[0] += l0.x * r; acc[1] += l0.y * r; acc[2] += l0.z * r; acc[3] += l0.w * r;
            acc[4] += l1.x * r; acc[5] += l1.y * r; acc[6] += l1.z * r; acc[7] += l1.w * r;
        }
#pragma unroll
        for (int i = 0; i < 8; ++i) M1[p0 + i][lane] = acc[i];
    }
    {
        float acc[8];
#pragma unroll
        for (int i = 0; i < 8; ++i) acc[i] = 0.f;
        for (int a = 0; a < 64; ++a) {
            const float r = Bk[a][lane];
            const float4 l0 = *(const float4*)&Gs[a][p0];
            const float4 l1 = *(const float4*)&Gs[a][p0 + 4];
            acc[0] += l0.x * r; acc[1] += l0.y * r; acc[2] += l0.z * r; acc[3] += l0.w * r;
            acc[4] += l1.x * r; acc[5] += l1.y * r; acc[6] += l1.z * r; acc[7] += l1.w * r;
        }
#pragma unroll
        for (int i = 0; i < 8; ++i) M2[p0 + i][lane] = acc[i];
    }
    __syncthreads();

    // P2: norms
    if (tid < 64) {
        float s = 0.f;
        for (int a = 0; a < 64; ++a) s += Bq[a][tid] * M1[a][tid];
        qin[tid] = 1.f / fmaxf(sqrtf(s), 1e-12f);
    } else if (tid < 128) {
        const int d = tid - 64;
        float s = 0.f;
        for (int a = 0; a < 64; ++a) s += Bk[a][d] * M2[a][d];
        kin[d] = 1.f / fmaxf(sqrtf(s), 1e-12f);
    }
    __syncthreads();

    // P3: S[d][e] = rs*kin[d]*qin[e] * sum_a Wk[a][d]*M1[a][e]; also load WvT into Bq
    const float rs = rescale[h];
    {
        float acc[8];
#pragma unroll
        for (int i = 0; i < 8; ++i) acc[i] = 0.f;
        for (int a = 0; a < 64; ++a) {
            const float r = M1[a][lane];
            const float4 l0 = *(const float4*)&Bk[a][p0];
            const float4 l1 = *(const float4*)&Bk[a][p0 + 4];
            acc[0] += l0.x * r; acc[1] += l0.y * r; acc[2] += l0.z * r; acc[3] += l0.w * r;
            acc[4] += l1.x * r; acc[5] += l1.y * r; acc[6] += l1.z * r; acc[7] += l1.w * r;
        }
        const float qv = qin[lane] * rs;
#pragma unroll
        for (int i = 0; i < 8; ++i) Sb[p0 + i][lane] = acc[i] * (kin[p0 + i] * qv);
    }
    for (int idx = tid; idx < 4096; idx += 512) {
        const int a = idx >> 6, e = idx & 63;
        Bq[e][a] = w_qkv[a * 768 + 512 + h * 64 + e];  // WvT[e][a]
    }
    __syncthreads();

    // P4: row softmax -> PT[e][d]
    if (tid < 64) {
        const int d = tid;
        float m = -1e30f;
        for (int e = 0; e < 64; ++e) m = fmaxf(m, Sb[d][e]);
        float s = 0.f;
        for (int e = 0; e < 64; ++e) {
            const float pv = expf(Sb[d][e] - m);
            s += pv;
            PT[e][d] = pv;
        }
        const float inv = 1.f / s;
        for (int e = 0; e < 64; ++e) PT[e][d] *= inv;
    }
    __syncthreads();

    // P5: ZT[d][a] = sum_e PT[e][d] * WvT[e][a]   (into M2)
    {
        float acc[8];
#pragma unroll
        for (int i = 0; i < 8; ++i) acc[i] = 0.f;
        for (int e = 0; e < 64; ++e) {
            const float r = Bq[e][lane];
            const float4 l0 = *(const float4*)&PT[e][p0];
            const float4 l1 = *(const float4*)&PT[e][p0 + 4];
            acc[0] += l0.x * r; acc[1] += l0.y * r; acc[2] += l0.z * r; acc[3] += l0.w * r;
            acc[4] += l1.x * r; acc[5] += l1.y * r; acc[6] += l1.z * r; acc[7] += l1.w * r;
        }
        __syncthreads();  // M2 (old G@Wk) fully consumed; order writes vs any stragglers
#pragma unroll
        for (int i = 0; i < 8; ++i) M2[p0 + i][lane] = acc[i];
    }
    __syncthreads();

    // P6: Wf_h[a][c] = sum_d ZT[d][a] * Wp[d][c]; atomic accumulate over heads
    {
        float acc[8];
#pragma unroll
        for (int i = 0; i < 8; ++i) acc[i] = 0.f;
        for (int d = 0; d < 64; ++d) {
            const float r = Bp[d][lane];
            const float4 l0 = *(const float4*)&M2[d][p0];
            const float4 l1 = *(const float4*)&M2[d][p0 + 4];
            acc[0] += l0.x * r; acc[1] += l0.y * r; acc[2] += l0.z * r; acc[3] += l0.w * r;
            acc[4] += l1.x * r; acc[5] += l1.y * r; acc[6] += l1.z * r; acc[7] += l1.w * r;
        }
#pragma unroll
        for (int i = 0; i < 8; ++i) atomicAdd(&wf[(p0 + i) * 64 + lane], acc[i]);
    }
}

// ---------------- K4: out = x @ Wf + b_proj ----------------
// 512 blocks x 256 thr; each block: 256 tokens (4 strips of 64)
__global__ __launch_bounds__(256) void k_out(const float* __restrict__ x,
                                             const float* __restrict__ wf_g,
                                             const float* __restrict__ b_proj,
                                             float* __restrict__ out) {
    __shared__ float wfs[64][64];
    __shared__ float xs[64][64];
    const int tid = threadIdx.x;
    const int c = tid & 63;
    const int q = tid >> 6;
    for (int idx = tid; idx < 4096; idx += 256) wfs[idx >> 6][idx & 63] = wf_g[idx];
    __syncthreads();
    float wf[64];
#pragma unroll
    for (int j = 0; j < 64; ++j) wf[j] = wfs[j][c];
    const float bb = b_proj[c];
    const long base = (long)blockIdx.x * 256;
    for (int s = 0; s < 4; ++s) {
        const long v0 = base + s * 64;
        __syncthreads();
        const float4* src = (const float4*)(x + v0 * 64);
#pragma unroll
        for (int r = 0; r < 4; ++r) ((float4*)&xs[0][0])[tid + r * 256] = src[tid + r * 256];
        __syncthreads();
#pragma unroll
        for (int vi = 0; vi < 16; ++vi) {
            const int v = q * 16 + vi;
            float acc = bb;
#pragma unroll
            for (int j = 0; j < 64; j += 4) {
                const float4 xr = *(const float4*)&xs[v][j];
                acc += xr.x * wf[j] + xr.y * wf[j + 1] + xr.z * wf[j + 2] + xr.w * wf[j + 3];
            }
            out[(v0 + v) * 64 + c] = acc;
        }
    }
}

// ---------------- K5: fused depthwise conv3d -> gelu -> conv3d, += out -----
// grid 2048: (cg 0..7, tw 0..15, th 0..15); tile: full depth 8, 8x8 spatial, 8 channels
__global__ __launch_bounds__(256) void k_conv(const float* __restrict__ x,
                                              const float* __restrict__ w1,
                                              const float* __restrict__ w2,
                                              float* __restrict__ out) {
    __shared__ __hip_bfloat16 xt[12][12][12][8];  // 27.6KB (global d in [-2,10), zero-padded)
    __shared__ float y1[10][10][10][8];           // 32KB (gelu(conv1)), zero outside image
    const int tid = threadIdx.x;
    const int b = blockIdx.x;
    const int cg = b & 7;
    const int tw = (b >> 3) & 15;
    const int th = b >> 7;
    const int h0 = th * 8, w0 = tw * 8;
    const int cl = tid & 7;
    const int cglob = cg * 8 + cl;

    // zero xt
    uint32_t* xtu = (uint32_t*)&xt[0][0][0][0];
    for (int i = tid; i < 12 * 12 * 12 * 8 / 2; i += 256) xtu[i] = 0u;
    __syncthreads();
    // load valid region of x (bf16 in LDS; ample precision vs 2.8e-2 threshold)
    for (int e = tid; e < 1728 * 8; e += 256) {
        const int c = e & 7;
        const int vi = e >> 3;
        const int dd = vi / 144;
        const int rem = vi - dd * 144;
        const int hh = rem / 12;
        const int ww = rem - hh * 12;
        const int gd = dd - 2, gh = h0 + hh - 2, gw = w0 + ww - 2;
        if (gd >= 0 && gd < 8 && gh >= 0 && gh < 128 && gw >= 0 && gw < 128) {
            const float v = x[(((long)(gd * 128 + gh)) * 128 + gw) * 64 + cg * 8 + c];
            xt[dd][hh][ww][c] = __float2bfloat16(v);
        }
    }
    // per-thread channel weights
    float wr1[27], wr2[27];
#pragma unroll
    for (int o = 0; o < 27; ++o) {
        wr1[o] = w1[cglob * 27 + o];
        wr2[o] = w2[cglob * 27 + o];
    }
    __syncthreads();
    // y1 = gelu(conv1(x)), zeroed outside the image (conv2 pads y1 with zeros)
    for (int e = tid; e < 1000 * 8; e += 256) {
        const int c = e & 7;
        const int sp = e >> 3;
        const int di = sp / 100;
        const int rem = sp - di * 100;
        const int hi = rem / 10;
        const int wi = rem - hi * 10;
        const int gdp = di - 1, ghp = h0 + hi - 1, gwp = w0 + wi - 1;
        float val = 0.f;
        if (gdp >= 0 && gdp < 8 && ghp >= 0 && ghp < 128 && gwp >= 0 && gwp < 128) {
            float acc = 0.f;
#pragma unroll
            for (int od = 0; od < 3; ++od)
#pragma unroll
                for (int oh = 0; oh < 3; ++oh)
#pragma unroll
                    for (int ow = 0; ow < 3; ++ow)
                        acc += wr1[(od * 3 + oh) * 3 + ow] *
                               __bfloat162float(xt[di + od][hi + oh][wi + ow][c]);
            val = 0.5f * acc * (1.f + erff(acc * 0.70710678118654752f));
        }
        y1[di][hi][wi][c] = val;
    }
    __syncthreads();
    // conv2 and accumulate into out
    for (int e = tid; e < 512 * 8; e += 256) {
        const int c = e & 7;
        const int so = e >> 3;
        const int do_ = so >> 6;
        const int rem = so & 63;
        const int ho = rem >> 3;
        const int wo = rem & 7;
        float acc = 0.f;
#pragma unroll
        for (int od = 0; od < 3; ++od)
#pragma unroll
            for (int oh = 0; oh < 3; ++oh)
#pragma unroll
                for (int ow = 0; ow < 3; ++ow)
                    acc += wr2[(od * 3 + oh) * 3 + ow] * y1[do_ + od][ho + oh][wo + ow][c];
        const long oidx = (((long)(do_ * 128 + (h0 + ho))) * 128 + (w0 + wo)) * 64 + cglob;
        out[oidx] += acc;
    }
}

extern "C" void kernel_launch(void* const* d_in, const int* in_sizes, int n_in,
                              void* d_out, int out_size, void* d_ws, size_t ws_size,
                              hipStream_t stream) {
    const float* x       = (const float*)d_in[0];
    const float* w_qkv   = (const float*)d_in[1];
    const float* rescale = (const float*)d_in[2];
    const float* w_proj  = (const float*)d_in[3];
    const float* b_proj  = (const float*)d_in[4];
    const float* w_pe1   = (const float*)d_in[5];
    const float* w_pe2   = (const float*)d_in[6];
    float* out = (float*)d_out;

    float* G  = (float*)d_ws;   // 4096 floats (atomically accumulated)
    float* wf = G + 4096;       // 4096 floats (atomically accumulated)
    // Gram partials (1024*4096 f32 = 16MB) live in d_out; k_out overwrites it later.
    float* partial = out;

    hipMemsetAsync(G, 0, 8192 * sizeof(float), stream);  // zero G and wf
    k_gram<<<1024, 256, 0, stream>>>(x, partial);
    k_reduceG<<<256, 256, 0, stream>>>(partial, G);
    k_attn<<<4, 512, 0, stream>>>(G, w_qkv, rescale, w_proj, wf);
    k_out<<<512, 256, 0, stream>>>(x, wf, b_proj, out);
    k_conv<<<2048, 256, 0, stream>>>(x, w_pe1, w_pe2, out);
}

// Round 4
// 234.777 us; speedup vs baseline: 1.3951x; 1.3951x over previous
//
#include <hip/hip_runtime.h>
#include <hip/hip_bf16.h>
#include <math.h>

// Problem constants: b=1, D=8, H=128, W=128, C=64; N = 131072 tokens.
// HEADS=4, DIM_HEAD=64, INNER=256.
// Math reformulation:
//   G = X^T X  (64x64)
//   attn_raw_h = Wk_h^T G Wq_h ; normalized by channel norms from G; softmax
//   W_final = sum_h (Wv_h @ P_h^T) @ Wp_h   (64x64)
//   out = X @ W_final + b_proj + dwconv2(gelu(dwconv1(X)))

#define NTOK 131072

// bf16 pack/unpack helpers (round-half-up; values are finite, far from overflow)
__device__ __forceinline__ uint32_t pk2(float a, float b) {
    return ((__float_as_uint(a) + 0x8000u) >> 16) |
           (((__float_as_uint(b) + 0x8000u) >> 16) << 16);
}
__device__ __forceinline__ float bl(uint32_t w) { return __uint_as_float(w << 16); }
__device__ __forceinline__ float bh(uint32_t w) { return __uint_as_float(w & 0xFFFF0000u); }

// ---------------- K1: Gram partials ----------------
// 1024 blocks x 256 thr; each block handles 128 tokens; partial[1024][64][64]
__global__ __launch_bounds__(256) void k_gram(const float* __restrict__ x,
                                              float* __restrict__ partial) {
    __shared__ float xs[16][64];
    const int tid = threadIdx.x;
    const int col = tid & 63;
    const int g = tid >> 6;  // 0..3 -> rows g*16..g*16+15
    float acc[16];
#pragma unroll
    for (int i = 0; i < 16; ++i) acc[i] = 0.f;
    const long tok0 = (long)blockIdx.x * 128;
    for (int t0 = 0; t0 < 128; t0 += 16) {
        __syncthreads();
        const float4* src = (const float4*)(x + (tok0 + t0) * 64);
        ((float4*)&xs[0][0])[tid] = src[tid];
        __syncthreads();
#pragma unroll
        for (int t = 0; t < 16; ++t) {
            const float xa = xs[t][col];
#pragma unroll
            for (int j = 0; j < 16; j += 4) {
                const float4 lv = *(const float4*)&xs[t][g * 16 + j];
                acc[j + 0] += lv.x * xa;
                acc[j + 1] += lv.y * xa;
                acc[j + 2] += lv.z * xa;
                acc[j + 3] += lv.w * xa;
            }
        }
    }
    float* p = partial + (size_t)blockIdx.x * 4096;
#pragma unroll
    for (int i = 0; i < 16; ++i) p[(g * 16 + i) * 64 + col] = acc[i];
}

// ---------------- K2: reduce partials -> G (atomic over 16 partial-slices) --
__global__ __launch_bounds__(256) void k_reduceG(const float* __restrict__ partial,
                                                 float* __restrict__ G) {
    const int pslice = blockIdx.x >> 4;
    const int eblk = blockIdx.x & 15;
    const int e = eblk * 256 + threadIdx.x;
    const float* p = partial + (size_t)pslice * 64 * 4096 + e;
    float s = 0.f;
#pragma unroll 8
    for (int i = 0; i < 64; ++i) s += p[(size_t)i * 4096];
    atomicAdd(&G[e], s);
}

// ---------------- K3: tiny attention algebra (4 blocks, one per head) ------
__global__ __launch_bounds__(512) void k_attn(const float* __restrict__ G,
                                              const float* __restrict__ w_qkv,
                                              const float* __restrict__ rescale,
                                              const float* __restrict__ w_proj,
                                              float* __restrict__ wf) {
    __shared__ float smem[6 * 4096 + 64 * 65];
    float (*Gs)[64] = (float(*)[64])smem;
    float (*PT)[64] = (float(*)[64])smem;  // alias (Gs dead after P1)
    float (*Bq)[64] = (float(*)[64])(smem + 4096);    // Wq, later WvT
    float (*Bk)[64] = (float(*)[64])(smem + 8192);    // Wk
    float (*Bp)[64] = (float(*)[64])(smem + 12288);   // Wp
    float (*M1)[64] = (float(*)[64])(smem + 16384);   // G@Wq
    float (*M2)[64] = (float(*)[64])(smem + 20480);   // G@Wk, later ZT
    float (*Sb)[65] = (float(*)[65])(smem + 24576);
    __shared__ float qin[64], kin[64];

    const int h = blockIdx.x;
    const int tid = threadIdx.x;
    const int lane = tid & 63;
    const int g = tid >> 6;      // 0..7
    const int p0 = g * 8;

    for (int idx = tid; idx < 4096; idx += 512) {
        const int a = idx >> 6, e = idx & 63;
        Gs[a][e] = G[idx];
        Bq[a][e] = w_qkv[a * 768 + h * 64 + e];
        Bk[a][e] = w_qkv[a * 768 + 256 + h * 64 + e];
        Bp[a][e] = w_proj[(h * 64 + a) * 64 + e];
    }
    __syncthreads();

    // P1: M1 = G@Wq, M2 = G@Wk (G symmetric)
    {
        float acc[8];
#pragma unroll
        for (int i = 0; i < 8; ++i) acc[i] = 0.f;
        for (int a = 0; a < 64; ++a) {
            const float r = Bq[a][lane];
            const float4 l0 = *(const float4*)&Gs[a][p0];
            const float4 l1 = *(const float4*)&Gs[a][p0 + 4];
            acc[0] += l0.x * r; acc[1] += l0.y * r; acc[2] += l0.z * r; acc[3] += l0.w * r;
            acc[4] += l1.x * r; acc[5] += l1.y * r; acc[6] += l1.z * r; acc[7] += l1.w * r;
        }
#pragma unroll
        for (int i = 0; i < 8; ++i) M1[p0 + i][lane] = acc[i];
    }
    {
        float acc[8];
#pragma unroll
        for (int i = 0; i < 8; ++i) acc[i] = 0.f;
        for (int a = 0; a < 64; ++a) {
            const float r = Bk[a][lane];
            const float4 l0 = *(const float4*)&Gs[a][p0];
            const float4 l1 = *(const float4*)&Gs[a][p0 + 4];
            acc[0] += l0.x * r; acc[1] += l0.y * r; acc[2] += l0.z * r; acc[3] += l0.w * r;
            acc[4] += l1.x * r; acc[5] += l1.y * r; acc[6] += l1.z * r; acc[7] += l1.w * r;
        }
#pragma unroll
        for (int i = 0; i < 8; ++i) M2[p0 + i][lane] = acc[i];
    }
    __syncthreads();

    // P2: norms
    if (tid < 64) {
        float s = 0.f;
        for (int a = 0; a < 64; ++a) s += Bq[a][tid] * M1[a][tid];
        qin[tid] = 1.f / fmaxf(sqrtf(s), 1e-12f);
    } else if (tid < 128) {
        const int d = tid - 64;
        float s = 0.f;
        for (int a = 0; a < 64; ++a) s += Bk[a][d] * M2[a][d];
        kin[d] = 1.f / fmaxf(sqrtf(s), 1e-12f);
    }
    __syncthreads();

    // P3: S = scaled Wk^T G Wq; also stage WvT into Bq
    const float rs = rescale[h];
    {
        float acc[8];
#pragma unroll
        for (int i = 0; i < 8; ++i) acc[i] = 0.f;
        for (int a = 0; a < 64; ++a) {
            const float r = M1[a][lane];
            const float4 l0 = *(const float4*)&Bk[a][p0];
            const float4 l1 = *(const float4*)&Bk[a][p0 + 4];
            acc[0] += l0.x * r; acc[1] += l0.y * r; acc[2] += l0.z * r; acc[3] += l0.w * r;
            acc[4] += l1.x * r; acc[5] += l1.y * r; acc[6] += l1.z * r; acc[7] += l1.w * r;
        }
        const float qv = qin[lane] * rs;
#pragma unroll
        for (int i = 0; i < 8; ++i) Sb[p0 + i][lane] = acc[i] * (kin[p0 + i] * qv);
    }
    for (int idx = tid; idx < 4096; idx += 512) {
        const int a = idx >> 6, e = idx & 63;
        Bq[e][a] = w_qkv[a * 768 + 512 + h * 64 + e];  // WvT[e][a]
    }
    __syncthreads();

    // P4: row softmax -> PT[e][d]
    if (tid < 64) {
        const int d = tid;
        float m = -1e30f;
        for (int e = 0; e < 64; ++e) m = fmaxf(m, Sb[d][e]);
        float s = 0.f;
        for (int e = 0; e < 64; ++e) {
            const float pv = expf(Sb[d][e] - m);
            s += pv;
            PT[e][d] = pv;
        }
        const float inv = 1.f / s;
        for (int e = 0; e < 64; ++e) PT[e][d] *= inv;
    }
    __syncthreads();

    // P5: ZT[d][a] = sum_e PT[e][d] * WvT[e][a]   (into M2)
    {
        float acc[8];
#pragma unroll
        for (int i = 0; i < 8; ++i) acc[i] = 0.f;
        for (int e = 0; e < 64; ++e) {
            const float r = Bq[e][lane];
            const float4 l0 = *(const float4*)&PT[e][p0];
            const float4 l1 = *(const float4*)&PT[e][p0 + 4];
            acc[0] += l0.x * r; acc[1] += l0.y * r; acc[2] += l0.z * r; acc[3] += l0.w * r;
            acc[4] += l1.x * r; acc[5] += l1.y * r; acc[6] += l1.z * r; acc[7] += l1.w * r;
        }
        __syncthreads();
#pragma unroll
        for (int i = 0; i < 8; ++i) M2[p0 + i][lane] = acc[i];
    }
    __syncthreads();

    // P6: Wf_h = ZT^T-combine with Wp; atomic accumulate over heads
    {
        float acc[8];
#pragma unroll
        for (int i = 0; i < 8; ++i) acc[i] = 0.f;
        for (int d = 0; d < 64; ++d) {
            const float r = Bp[d][lane];
            const float4 l0 = *(const float4*)&M2[d][p0];
            const float4 l1 = *(const float4*)&M2[d][p0 + 4];
            acc[0] += l0.x * r; acc[1] += l0.y * r; acc[2] += l0.z * r; acc[3] += l0.w * r;
            acc[4] += l1.x * r; acc[5] += l1.y * r; acc[6] += l1.z * r; acc[7] += l1.w * r;
        }
#pragma unroll
        for (int i = 0; i < 8; ++i) atomicAdd(&wf[(p0 + i) * 64 + lane], acc[i]);
    }
}

// ---------------- K4: out = x @ Wf + b_proj ----------------
__global__ __launch_bounds__(256) void k_out(const float* __restrict__ x,
                                             const float* __restrict__ wf_g,
                                             const float* __restrict__ b_proj,
                                             float* __restrict__ out) {
    __shared__ float wfs[64][64];
    __shared__ float xs[64][64];
    const int tid = threadIdx.x;
    const int c = tid & 63;
    const int q = tid >> 6;
    for (int idx = tid; idx < 4096; idx += 256) wfs[idx >> 6][idx & 63] = wf_g[idx];
    __syncthreads();
    float wf[64];
#pragma unroll
    for (int j = 0; j < 64; ++j) wf[j] = wfs[j][c];
    const float bb = b_proj[c];
    const long base = (long)blockIdx.x * 256;
    for (int s = 0; s < 4; ++s) {
        const long v0 = base + s * 64;
        __syncthreads();
        const float4* src = (const float4*)(x + v0 * 64);
#pragma unroll
        for (int r = 0; r < 4; ++r) ((float4*)&xs[0][0])[tid + r * 256] = src[tid + r * 256];
        __syncthreads();
#pragma unroll
        for (int vi = 0; vi < 16; ++vi) {
            const int v = q * 16 + vi;
            float acc = bb;
#pragma unroll
            for (int j = 0; j < 64; j += 4) {
                const float4 xr = *(const float4*)&xs[v][j];
                acc += xr.x * wf[j] + xr.y * wf[j + 1] + xr.z * wf[j + 2] + xr.w * wf[j + 3];
            }
            out[(v0 + v) * 64 + c] = acc;
        }
    }
}

// ---------------- K5: fused depthwise conv3d -> gelu -> conv3d, += out -----
// Column design: thread owns one (channel, hi, wi) column, computes all 8 depths
// from contiguous 24B bf16 LDS columns (3x ds_read_b64 per tap-column).
// Block b: xcd = b&7, tile = xcd*32 + ((b>>3)&31), cg = b>>8
//   -> all 8 cg-blocks of a tile map to the SAME XCD (b mod 8 = tile mod ... fixed),
//      dispatched 256 apart (co-resident) => x lines reused in that XCD's L2.
__global__ __launch_bounds__(256) void k_conv(const float* __restrict__ x,
                                              const float* __restrict__ w1,
                                              const float* __restrict__ w2,
                                              float* __restrict__ out) {
    // columns: stride 6 words = 24B (8B-aligned for b64; banks spread, worst 4-way)
    __shared__ uint32_t xt[12][12][8][6];  // 27648 B: dd = gd+2, dd 0,1,10,11 zero
    __shared__ uint32_t y1[10][10][8][6];  // 19200 B: k = dp+1, k 0,9 zero (pad planes)
    const int tid = threadIdx.x;
    const int b = blockIdx.x;
    const int xcd = b & 7, seq = (b >> 3) & 31, cg = b >> 8;
    const int tile = xcd * 32 + seq;
    const int tw = tile & 15, th = tile >> 4;
    const int h0 = th * 8, w0 = tw * 8;
    const int c = tid & 7;
    const int cglob = cg * 8 + c;

    // conv1 weights for this thread's channel
    float wr1[27];
#pragma unroll
    for (int o = 0; o < 27; ++o) wr1[o] = w1[cglob * 27 + o];

    // ---- load x tile -> bf16 columns (zero outside image) ----
    // tasks: 12x12 spatial x 8 ch = 1152; c stays tid&7 (stride 256 = 0 mod 8)
    for (int e = tid; e < 1152; e += 256) {
        const int sp = e >> 3;             // 0..143
        const int hh = sp / 12;
        const int ww = sp - hh * 12;
        const int gh = h0 + hh - 2, gw = w0 + ww - 2;
        uint32_t col[6] = {0u, 0u, 0u, 0u, 0u, 0u};
        if ((unsigned)gh < 128u && (unsigned)gw < 128u) {
            const float* xp = x + ((long)gh * 128 + gw) * 64 + cglob;
            float v[8];
#pragma unroll
            for (int gd = 0; gd < 8; ++gd) v[gd] = xp[(long)gd * 1048576];
            col[1] = pk2(v[0], v[1]);
            col[2] = pk2(v[2], v[3]);
            col[3] = pk2(v[4], v[5]);
            col[4] = pk2(v[6], v[7]);
        }
        uint32_t* dst = &xt[hh][ww][e & 7][0];
        *(uint2*)(dst + 0) = make_uint2(col[0], col[1]);
        *(uint2*)(dst + 2) = make_uint2(col[2], col[3]);
        *(uint2*)(dst + 4) = make_uint2(col[4], col[5]);
    }
    __syncthreads();

    // ---- conv1 + gelu -> y1 columns ----
    // tasks: 10x10 spatial x 8 ch = 800
    for (int e = tid; e < 800; e += 256) {
        const int sp = e >> 3;             // 0..99
        const int hi_ = sp / 10;
        const int wi = sp - hi_ * 10;
        const int ghp = h0 + hi_ - 1, gwp = w0 + wi - 1;
        uint32_t ow_[6];
        if ((unsigned)ghp < 128u && (unsigned)gwp < 128u) {
            float acc[8];
#pragma unroll
            for (int j = 0; j < 8; ++j) acc[j] = 0.f;
#pragma unroll
            for (int oh = 0; oh < 3; ++oh) {
#pragma unroll
                for (int ow = 0; ow < 3; ++ow) {
                    const uint32_t* cp = &xt[hi_ + oh][wi + ow][e & 7][0];
                    const uint2 wa = *(const uint2*)(cp + 0);   // elems 0,1 | 2,3
                    const uint2 wb = *(const uint2*)(cp + 2);   // elems 4,5 | 6,7
                    const uint2 wc = *(const uint2*)(cp + 4);   // elems 8,9 | 10,11
                    float xc[12];
                    xc[1] = bh(wa.x);
                    xc[2] = bl(wa.y); xc[3] = bh(wa.y);
                    xc[4] = bl(wb.x); xc[5] = bh(wb.x);
                    xc[6] = bl(wb.y); xc[7] = bh(wb.y);
                    xc[8] = bl(wc.x); xc[9] = bh(wc.x);
                    xc[10] = bl(wc.y);
                    const float wg0 = wr1[oh * 3 + ow];
                    const float wg1 = wr1[9 + oh * 3 + ow];
                    const float wg2 = wr1[18 + oh * 3 + ow];
#pragma unroll
                    for (int j = 0; j < 8; ++j)
                        acc[j] += wg0 * xc[j + 1] + wg1 * xc[j + 2] + wg2 * xc[j + 3];
                }
            }
            float gl[8];
#pragma unroll
            for (int j = 0; j < 8; ++j)
                gl[j] = 0.5f * acc[j] * (1.f + erff(acc[j] * 0.70710678118654752f));
            ow_[0] = pk2(0.f, gl[0]);
            ow_[1] = pk2(gl[1], gl[2]);
            ow_[2] = pk2(gl[3], gl[4]);
            ow_[3] = pk2(gl[5], gl[6]);
            ow_[4] = pk2(gl[7], 0.f);
            ow_[5] = 0u;
        } else {
#pragma unroll
            for (int i = 0; i < 6; ++i) ow_[i] = 0u;
        }
        uint32_t* dst = &y1[hi_][wi][e & 7][0];
        *(uint2*)(dst + 0) = make_uint2(ow_[0], ow_[1]);
        *(uint2*)(dst + 2) = make_uint2(ow_[2], ow_[3]);
        *(uint2*)(dst + 4) = make_uint2(ow_[4], ow_[5]);
    }

    // conv2 weights (separate lifetime from wr1)
    float wr2[27];
#pragma unroll
    for (int o = 0; o < 27; ++o) wr2[o] = w2[cglob * 27 + o];
    __syncthreads();

    // ---- conv2 -> out (RMW add) ----
    // tasks: 8x8 spatial x 8 ch = 512 (exactly 2 iters)
    for (int e = tid; e < 512; e += 256) {
        const int sp = e >> 3;             // 0..63
        const int ho = sp >> 3, wo = sp & 7;
        float a2[8];
#pragma unroll
        for (int j = 0; j < 8; ++j) a2[j] = 0.f;
#pragma unroll
        for (int oh = 0; oh < 3; ++oh) {
#pragma unroll
            for (int ow = 0; ow < 3; ++ow) {
                const uint32_t* cp = &y1[ho + oh][wo + ow][e & 7][0];
                const uint2 wa = *(const uint2*)(cp + 0);   // k 0,1 | 2,3
                const uint2 wb = *(const uint2*)(cp + 2);   // k 4,5 | 6,7
                const uint32_t wcw = cp[4];                 // k 8,9
                float yc[10];
                yc[0] = bl(wa.x); yc[1] = bh(wa.x);
                yc[2] = bl(wa.y); yc[3] = bh(wa.y);
                yc[4] = bl(wb.x); yc[5] = bh(wb.x);
                yc[6] = bl(wb.y); yc[7] = bh(wb.y);
                yc[8] = bl(wcw);  yc[9] = bh(wcw);
                const float wg0 = wr2[oh * 3 + ow];
                const float wg1 = wr2[9 + oh * 3 + ow];
                const float wg2 = wr2[18 + oh * 3 + ow];
#pragma unroll
                for (int j = 0; j < 8; ++j)
                    a2[j] += wg0 * yc[j] + wg1 * yc[j + 1] + wg2 * yc[j + 2];
            }
        }
        const int gh = h0 + ho, gw = w0 + wo;
        float* op = out + ((long)gh * 128 + gw) * 64 + cglob;
#pragma unroll
        for (int j = 0; j < 8; ++j) op[(long)j * 1048576] += a2[j];
    }
}

extern "C" void kernel_launch(void* const* d_in, const int* in_sizes, int n_in,
                              void* d_out, int out_size, void* d_ws, size_t ws_size,
                              hipStream_t stream) {
    const float* x       = (const float*)d_in[0];
    const float* w_qkv   = (const float*)d_in[1];
    const float* rescale = (const float*)d_in[2];
    const float* w_proj  = (const float*)d_in[3];
    const float* b_proj  = (const float*)d_in[4];
    const float* w_pe1   = (const float*)d_in[5];
    const float* w_pe2   = (const float*)d_in[6];
    float* out = (float*)d_out;

    float* G  = (float*)d_ws;   // 4096 floats (atomically accumulated)
    float* wf = G + 4096;       // 4096 floats (atomically accumulated)
    // Gram partials (1024*4096 f32 = 16MB) live in d_out; k_out overwrites later.
    float* partial = out;

    hipMemsetAsync(G, 0, 8192 * sizeof(float), stream);  // zero G and wf
    k_gram<<<1024, 256, 0, stream>>>(x, partial);
    k_reduceG<<<256, 256, 0, stream>>>(partial, G);
    k_attn<<<4, 512, 0, stream>>>(G, w_qkv, rescale, w_proj, wf);
    k_out<<<512, 256, 0, stream>>>(x, wf, b_proj, out);
    k_conv<<<2048, 256, 0, stream>>>(x, w_pe1, w_pe2, out);
}

// Round 5
// 233.314 us; speedup vs baseline: 1.4039x; 1.0063x over previous
//
#include <hip/hip_runtime.h>
#include <hip/hip_bf16.h>
#include <math.h>

// Problem constants: b=1, D=8, H=128, W=128, C=64; N = 131072 tokens.
// Math reformulation:
//   G = X^T X  (64x64), via split-bf16 MFMA: X = Xh + Xl;
//     G ≈ Xh^TXh + Xh^TXl + Xl^TXh  (symmetric; Xl^TXl ~1e-10 rel, dropped)
//   attn_raw_h = Wk_h^T G Wq_h ; normalized by channel norms from G; softmax
//   W_final = sum_h (Wv_h @ P_h^T) @ Wp_h   (64x64)
//   out = X @ W_final + b_proj + dwconv2(gelu(dwconv1(X)))

#define NTOK 131072

typedef __attribute__((ext_vector_type(8))) short short8v;
typedef __attribute__((ext_vector_type(4))) float f32x4;

// bf16 pack/unpack helpers (round-half-up; fine since lo-term corrects hi rounding)
__device__ __forceinline__ uint32_t pk2(float a, float b) {
    return ((__float_as_uint(a) + 0x8000u) >> 16) |
           (((__float_as_uint(b) + 0x8000u) >> 16) << 16);
}
__device__ __forceinline__ float bl(uint32_t w) { return __uint_as_float(w << 16); }
__device__ __forceinline__ float bh(uint32_t w) { return __uint_as_float(w & 0xFFFF0000u); }

// ---------------- K1: Gram via MFMA, per-wave partials ----------------
// 512 blocks x 256 thr (4 waves). Wave g owns tokens [g*64, g*64+64), 2 steps of 32.
// Per step: lane loads 4 ranges x 8 tokens f32 direct from global (64B segments),
// converts to bf16 hi/lo frags, 10 symmetric tiles x 3 MFMA.
// partial[g][10][16][16]  (2048 waves x 2560 f32 = 21MB, lives in d_out)
__global__ __launch_bounds__(256) void k_gram(const float* __restrict__ x,
                                              float* __restrict__ partial) {
    const int tid = threadIdx.x;
    const int lane = tid & 63;
    const int wave = tid >> 6;
    const int gwave = blockIdx.x * 4 + wave;   // 0..2047
    const int lh = lane >> 4;                  // token subgroup 0..3
    const int lc = lane & 15;                  // channel within range
    f32x4 acc[10];
#pragma unroll
    for (int t = 0; t < 10; ++t) acc[t] = (f32x4){0.f, 0.f, 0.f, 0.f};
    const long tokBase = (long)gwave * 64;
#pragma unroll
    for (int s = 0; s < 2; ++s) {
        const long t0 = tokBase + s * 32 + lh * 8;
        float v[4][8];
#pragma unroll
        for (int r = 0; r < 4; ++r) {
            const float* p = x + t0 * 64 + r * 16 + lc;
#pragma unroll
            for (int i = 0; i < 8; ++i) v[r][i] = p[i * 64];
        }
        union { short8v s8; uint32_t u[4]; } fh[4], fl[4];
#pragma unroll
        for (int r = 0; r < 4; ++r) {
#pragma unroll
            for (int w = 0; w < 4; ++w) {
                const float a = v[r][2 * w], b = v[r][2 * w + 1];
                const uint32_t hw = pk2(a, b);
                fh[r].u[w] = hw;
                fl[r].u[w] = pk2(a - bl(hw), b - bh(hw));
            }
        }
#pragma unroll
        for (int td = 0; td < 4; ++td) {
#pragma unroll
            for (int te = td; te < 4; ++te) {
                const int t = td * 4 + te - (td * (td + 1)) / 2;
                acc[t] = __builtin_amdgcn_mfma_f32_16x16x32_bf16(fh[td].s8, fh[te].s8, acc[t], 0, 0, 0);
                acc[t] = __builtin_amdgcn_mfma_f32_16x16x32_bf16(fh[td].s8, fl[te].s8, acc[t], 0, 0, 0);
                acc[t] = __builtin_amdgcn_mfma_f32_16x16x32_bf16(fl[td].s8, fh[te].s8, acc[t], 0, 0, 0);
            }
        }
    }
    // C/D layout: col = lane&15, row = (lane>>4)*4 + reg   [verified m89]
    float* pb = partial + (size_t)gwave * 2560;
#pragma unroll
    for (int t = 0; t < 10; ++t)
#pragma unroll
        for (int j = 0; j < 4; ++j)
            pb[t * 256 + (lh * 4 + j) * 16 + lc] = acc[t][j];
}

// ---------------- K2: reduce wave-partials -> G (symmetric indexing) ------
// grid 512: (slice 0..31) x (eblk 0..15); thread sums 64 partials, atomicAdd.
__global__ __launch_bounds__(256) void k_reduceG(const float* __restrict__ partial,
                                                 float* __restrict__ G) {
    const int entry = (blockIdx.x & 15) * 256 + threadIdx.x;  // 0..4095
    const int slice = blockIdx.x >> 4;                        // 0..31
    const int d = entry >> 6, e = entry & 63;
    int td = d >> 4, te = e >> 4, r = d & 15, c = e & 15;
    if (td > te) { int t = td; td = te; te = t; t = r; r = c; c = t; }
    const int off = (td * 4 + te - (td * (td + 1)) / 2) * 256 + r * 16 + c;
    const float* p = partial + (size_t)slice * 64 * 2560 + off;
    float s = 0.f;
#pragma unroll 8
    for (int i = 0; i < 64; ++i) s += p[(size_t)i * 2560];
    atomicAdd(&G[entry], s);
}

// ---------------- K3: tiny attention algebra (4 blocks, one per head) ------
__global__ __launch_bounds__(512) void k_attn(const float* __restrict__ G,
                                              const float* __restrict__ w_qkv,
                                              const float* __restrict__ rescale,
                                              const float* __restrict__ w_proj,
                                              float* __restrict__ wf) {
    __shared__ float smem[6 * 4096 + 64 * 65];
    float (*Gs)[64] = (float(*)[64])smem;
    float (*PT)[64] = (float(*)[64])smem;  // alias (Gs dead after P1)
    float (*Bq)[64] = (float(*)[64])(smem + 4096);    // Wq, later WvT
    float (*Bk)[64] = (float(*)[64])(smem + 8192);    // Wk
    float (*Bp)[64] = (float(*)[64])(smem + 12288);   // Wp
    float (*M1)[64] = (float(*)[64])(smem + 16384);   // G@Wq
    float (*M2)[64] = (float(*)[64])(smem + 20480);   // G@Wk, later ZT
    float (*Sb)[65] = (float(*)[65])(smem + 24576);
    __shared__ float qin[64], kin[64];

    const int h = blockIdx.x;
    const int tid = threadIdx.x;
    const int lane = tid & 63;
    const int g = tid >> 6;      // 0..7
    const int p0 = g * 8;

    for (int idx = tid; idx < 4096; idx += 512) {
        const int a = idx >> 6, e = idx & 63;
        Gs[a][e] = G[idx];
        Bq[a][e] = w_qkv[a * 768 + h * 64 + e];
        Bk[a][e] = w_qkv[a * 768 + 256 + h * 64 + e];
        Bp[a][e] = w_proj[(h * 64 + a) * 64 + e];
    }
    __syncthreads();

    // P1: M1 = G@Wq, M2 = G@Wk (G symmetric)
    {
        float acc[8];
#pragma unroll
        for (int i = 0; i < 8; ++i) acc[i] = 0.f;
        for (int a = 0; a < 64; ++a) {
            const float r = Bq[a][lane];
            const float4 l0 = *(const float4*)&Gs[a][p0];
            const float4 l1 = *(const float4*)&Gs[a][p0 + 4];
            acc[0] += l0.x * r; acc[1] += l0.y * r; acc[2] += l0.z * r; acc[3] += l0.w * r;
            acc[4] += l1.x * r; acc[5] += l1.y * r; acc[6] += l1.z * r; acc[7] += l1.w * r;
        }
#pragma unroll
        for (int i = 0; i < 8; ++i) M1[p0 + i][lane] = acc[i];
    }
    {
        float acc[8];
#pragma unroll
        for (int i = 0; i < 8; ++i) acc[i] = 0.f;
        for (int a = 0; a < 64; ++a) {
            const float r = Bk[a][lane];
            const float4 l0 = *(const float4*)&Gs[a][p0];
            const float4 l1 = *(const float4*)&Gs[a][p0 + 4];
            acc[0] += l0.x * r; acc[1] += l0.y * r; acc[2] += l0.z * r; acc[3] += l0.w * r;
            acc[4] += l1.x * r; acc[5] += l1.y * r; acc[6] += l1.z * r; acc[7] += l1.w * r;
        }
#pragma unroll
        for (int i = 0; i < 8; ++i) M2[p0 + i][lane] = acc[i];
    }
    __syncthreads();

    // P2: norms
    if (tid < 64) {
        float s = 0.f;
        for (int a = 0; a < 64; ++a) s += Bq[a][tid] * M1[a][tid];
        qin[tid] = 1.f / fmaxf(sqrtf(s), 1e-12f);
    } else if (tid < 128) {
        const int d = tid - 64;
        float s = 0.f;
        for (int a = 0; a < 64; ++a) s += Bk[a][d] * M2[a][d];
        kin[d] = 1.f / fmaxf(sqrtf(s), 1e-12f);
    }
    __syncthreads();

    // P3: S = scaled Wk^T G Wq; also stage WvT into Bq
    const float rs = rescale[h];
    {
        float acc[8];
#pragma unroll
        for (int i = 0; i < 8; ++i) acc[i] = 0.f;
        for (int a = 0; a < 64; ++a) {
            const float r = M1[a][lane];
            const float4 l0 = *(const float4*)&Bk[a][p0];
            const float4 l1 = *(const float4*)&Bk[a][p0 + 4];
            acc[0] += l0.x * r; acc[1] += l0.y * r; acc[2] += l0.z * r; acc[3] += l0.w * r;
            acc[4] += l1.x * r; acc[5] += l1.y * r; acc[6] += l1.z * r; acc[7] += l1.w * r;
        }
        const float qv = qin[lane] * rs;
#pragma unroll
        for (int i = 0; i < 8; ++i) Sb[p0 + i][lane] = acc[i] * (kin[p0 + i] * qv);
    }
    for (int idx = tid; idx < 4096; idx += 512) {
        const int a = idx >> 6, e = idx & 63;
        Bq[e][a] = w_qkv[a * 768 + 512 + h * 64 + e];  // WvT[e][a]
    }
    __syncthreads();

    // P4: row softmax -> PT[e][d]
    if (tid < 64) {
        const int d = tid;
        float m = -1e30f;
        for (int e = 0; e < 64; ++e) m = fmaxf(m, Sb[d][e]);
        float s = 0.f;
        for (int e = 0; e < 64; ++e) {
            const float pv = expf(Sb[d][e] - m);
            s += pv;
            PT[e][d] = pv;
        }
        const float inv = 1.f / s;
        for (int e = 0; e < 64; ++e) PT[e][d] *= inv;
    }
    __syncthreads();

    // P5: ZT[d][a] = sum_e PT[e][d] * WvT[e][a]   (into M2)
    {
        float acc[8];
#pragma unroll
        for (int i = 0; i < 8; ++i) acc[i] = 0.f;
        for (int e = 0; e < 64; ++e) {
            const float r = Bq[e][lane];
            const float4 l0 = *(const float4*)&PT[e][p0];
            const float4 l1 = *(const float4*)&PT[e][p0 + 4];
            acc[0] += l0.x * r; acc[1] += l0.y * r; acc[2] += l0.z * r; acc[3] += l0.w * r;
            acc[4] += l1.x * r; acc[5] += l1.y * r; acc[6] += l1.z * r; acc[7] += l1.w * r;
        }
        __syncthreads();
#pragma unroll
        for (int i = 0; i < 8; ++i) M2[p0 + i][lane] = acc[i];
    }
    __syncthreads();

    // P6: Wf_h = ZT combine with Wp; atomic accumulate over heads
    {
        float acc[8];
#pragma unroll
        for (int i = 0; i < 8; ++i) acc[i] = 0.f;
        for (int d = 0; d < 64; ++d) {
            const float r = Bp[d][lane];
            const float4 l0 = *(const float4*)&M2[d][p0];
            const float4 l1 = *(const float4*)&M2[d][p0 + 4];
            acc[0] += l0.x * r; acc[1] += l0.y * r; acc[2] += l0.z * r; acc[3] += l0.w * r;
            acc[4] += l1.x * r; acc[5] += l1.y * r; acc[6] += l1.z * r; acc[7] += l1.w * r;
        }
#pragma unroll
        for (int i = 0; i < 8; ++i) atomicAdd(&wf[(p0 + i) * 64 + lane], acc[i]);
    }
}

// ---------------- K4: out = x @ Wf + b_proj ----------------
__global__ __launch_bounds__(256) void k_out(const float* __restrict__ x,
                                             const float* __restrict__ wf_g,
                                             const float* __restrict__ b_proj,
                                             float* __restrict__ out) {
    __shared__ float wfs[64][64];
    __shared__ float xs[64][64];
    const int tid = threadIdx.x;
    const int c = tid & 63;
    const int q = tid >> 6;
    for (int idx = tid; idx < 4096; idx += 256) wfs[idx >> 6][idx & 63] = wf_g[idx];
    __syncthreads();
    float wf[64];
#pragma unroll
    for (int j = 0; j < 64; ++j) wf[j] = wfs[j][c];
    const float bb = b_proj[c];
    const long base = (long)blockIdx.x * 256;
    for (int s = 0; s < 4; ++s) {
        const long v0 = base + s * 64;
        __syncthreads();
        const float4* src = (const float4*)(x + v0 * 64);
#pragma unroll
        for (int r = 0; r < 4; ++r) ((float4*)&xs[0][0])[tid + r * 256] = src[tid + r * 256];
        __syncthreads();
#pragma unroll
        for (int vi = 0; vi < 16; ++vi) {
            const int v = q * 16 + vi;
            float acc = bb;
#pragma unroll
            for (int j = 0; j < 64; j += 4) {
                const float4 xr = *(const float4*)&xs[v][j];
                acc += xr.x * wf[j] + xr.y * wf[j + 1] + xr.z * wf[j + 2] + xr.w * wf[j + 3];
            }
            out[(v0 + v) * 64 + c] = acc;
        }
    }
}

// ---------------- K5: fused depthwise conv3d -> gelu -> conv3d, += out -----
// Column design: thread owns one (channel, hi, wi) column, all 8 depths.
// 5-word (20B) bf16 columns store only the 10 live depth slots -> 39KB LDS
// -> 4 blocks/CU. b32 LDS reads (20B stride is not 8B-aligned).
__global__ __launch_bounds__(256) void k_conv(const float* __restrict__ x,
                                              const float* __restrict__ w1,
                                              const float* __restrict__ w2,
                                              float* __restrict__ out) {
    __shared__ uint32_t xt[12][12][8][5];  // 23040B: slots dd=1..10 (gd=dd-2)
    __shared__ uint32_t y1[10][10][8][5];  // 16000B: slots k=0..9  (dp=k-1)
    const int tid = threadIdx.x;
    const int b = blockIdx.x;
    const int xcd = b & 7, seq = (b >> 3) & 31, cg = b >> 8;
    const int tile = xcd * 32 + seq;
    const int tw = tile & 15, th = tile >> 4;
    const int h0 = th * 8, w0 = tw * 8;
    const int c = tid & 7;
    const int cglob = cg * 8 + c;

    float wr1[27];
#pragma unroll
    for (int o = 0; o < 27; ++o) wr1[o] = w1[cglob * 27 + o];

    // ---- load x tile -> bf16 columns (zero outside image) ----
    for (int e = tid; e < 1152; e += 256) {
        const int sp = e >> 3;             // 0..143
        const int hh = sp / 12;
        const int ww = sp - hh * 12;
        const int gh = h0 + hh - 2, gw = w0 + ww - 2;
        uint32_t col[5] = {0u, 0u, 0u, 0u, 0u};
        if ((unsigned)gh < 128u && (unsigned)gw < 128u) {
            const float* xp = x + ((long)gh * 128 + gw) * 64 + cglob;
            float v[8];
#pragma unroll
            for (int gd = 0; gd < 8; ++gd) v[gd] = xp[(long)gd * 1048576];
            col[0] = pk2(0.f, v[0]);       // dd=1(pad), dd=2
            col[1] = pk2(v[1], v[2]);      // dd=3,4
            col[2] = pk2(v[3], v[4]);      // dd=5,6
            col[3] = pk2(v[5], v[6]);      // dd=7,8
            col[4] = pk2(v[7], 0.f);       // dd=9, dd=10(pad)
        }
        uint32_t* dst = &xt[hh][ww][e & 7][0];
#pragma unroll
        for (int i = 0; i < 5; ++i) dst[i] = col[i];
    }
    __syncthreads();

    // ---- conv1 + gelu -> y1 columns ----
    for (int e = tid; e < 800; e += 256) {
        const int sp = e >> 3;             // 0..99
        const int hi_ = sp / 10;
        const int wi = sp - hi_ * 10;
        const int ghp = h0 + hi_ - 1, gwp = w0 + wi - 1;
        uint32_t ow_[5];
        if ((unsigned)ghp < 128u && (unsigned)gwp < 128u) {
            float acc[8];
#pragma unroll
            for (int j = 0; j < 8; ++j) acc[j] = 0.f;
#pragma unroll
            for (int oh = 0; oh < 3; ++oh) {
#pragma unroll
                for (int ow = 0; ow < 3; ++ow) {
                    const uint32_t* cp = &xt[hi_ + oh][wi + ow][e & 7][0];
                    float xc[11];  // xc[1..10] = slots dd=1..10
#pragma unroll
                    for (int wdx = 0; wdx < 5; ++wdx) {
                        const uint32_t wv = cp[wdx];
                        xc[2 * wdx + 1] = bl(wv);
                        xc[2 * wdx + 2] = bh(wv);
                    }
                    const float wg0 = wr1[oh * 3 + ow];
                    const float wg1 = wr1[9 + oh * 3 + ow];
                    const float wg2 = wr1[18 + oh * 3 + ow];
#pragma unroll
                    for (int j = 0; j < 8; ++j)
                        acc[j] += wg0 * xc[j + 1] + wg1 * xc[j + 2] + wg2 * xc[j + 3];
                }
            }
            float gl[8];
#pragma unroll
            for (int j = 0; j < 8; ++j)
                gl[j] = 0.5f * acc[j] * (1.f + erff(acc[j] * 0.70710678118654752f));
            ow_[0] = pk2(0.f, gl[0]);      // k=0(pad), k=1
            ow_[1] = pk2(gl[1], gl[2]);
            ow_[2] = pk2(gl[3], gl[4]);
            ow_[3] = pk2(gl[5], gl[6]);
            ow_[4] = pk2(gl[7], 0.f);      // k=8, k=9(pad)
        } else {
#pragma unroll
            for (int i = 0; i < 5; ++i) ow_[i] = 0u;
        }
        uint32_t* dst = &y1[hi_][wi][e & 7][0];
#pragma unroll
        for (int i = 0; i < 5; ++i) dst[i] = ow_[i];
    }

    float wr2[27];
#pragma unroll
    for (int o = 0; o < 27; ++o) wr2[o] = w2[cglob * 27 + o];
    __syncthreads();

    // ---- conv2 -> out (RMW add) ----
    for (int e = tid; e < 512; e += 256) {
        const int sp = e >> 3;             // 0..63
        const int ho = sp >> 3, wo = sp & 7;
        float a2[8];
#pragma unroll
        for (int j = 0; j < 8; ++j) a2[j] = 0.f;
#pragma unroll
        for (int oh = 0; oh < 3; ++oh) {
#pragma unroll
            for (int ow = 0; ow < 3; ++ow) {
                const uint32_t* cp = &y1[ho + oh][wo + ow][e & 7][0];
                float yc[10];  // slots k=0..9
#pragma unroll
                for (int wdx = 0; wdx < 5; ++wdx) {
                    const uint32_t wv = cp[wdx];
                    yc[2 * wdx] = bl(wv);
                    yc[2 * wdx + 1] = bh(wv);
                }
                const float wg0 = wr2[oh * 3 + ow];
                const float wg1 = wr2[9 + oh * 3 + ow];
                const float wg2 = wr2[18 + oh * 3 + ow];
#pragma unroll
                for (int j = 0; j < 8; ++j)
                    a2[j] += wg0 * yc[j] + wg1 * yc[j + 1] + wg2 * yc[j + 2];
            }
        }
        const int gh = h0 + ho, gw = w0 + wo;
        float* op = out + ((long)gh * 128 + gw) * 64 + cglob;
#pragma unroll
        for (int j = 0; j < 8; ++j) op[(long)j * 1048576] += a2[j];
    }
}

extern "C" void kernel_launch(void* const* d_in, const int* in_sizes, int n_in,
                              void* d_out, int out_size, void* d_ws, size_t ws_size,
                              hipStream_t stream) {
    const float* x       = (const float*)d_in[0];
    const float* w_qkv   = (const float*)d_in[1];
    const float* rescale = (const float*)d_in[2];
    const float* w_proj  = (const float*)d_in[3];
    const float* b_proj  = (const float*)d_in[4];
    const float* w_pe1   = (const float*)d_in[5];
    const float* w_pe2   = (const float*)d_in[6];
    float* out = (float*)d_out;

    float* G  = (float*)d_ws;   // 4096 floats (atomically accumulated)
    float* wf = G + 4096;       // 4096 floats (atomically accumulated)
    // Gram wave-partials (2048 x 2560 f32 = 21MB) live in d_out; k_out overwrites later.
    float* partial = out;

    hipMemsetAsync(G, 0, 8192 * sizeof(float), stream);  // zero G and wf
    k_gram<<<512, 256, 0, stream>>>(x, partial);
    k_reduceG<<<512, 256, 0, stream>>>(partial, G);
    k_attn<<<4, 512, 0, stream>>>(G, w_qkv, rescale, w_proj, wf);
    k_out<<<512, 256, 0, stream>>>(x, wf, b_proj, out);
    k_conv<<<2048, 256, 0, stream>>>(x, w_pe1, w_pe2, out);
}

// Round 7
// 207.220 us; speedup vs baseline: 1.5807x; 1.1259x over previous
//
#include <hip/hip_runtime.h>
#include <hip/hip_bf16.h>
#include <math.h>

// Problem: b=1, D=8, H=128, W=128, C=64; N = 131072 tokens.
// Factored algebra:
//   G = X^T X (64x64, split-bf16 MFMA); channel norms + softmax on G-derived 64x64;
//   W_final = sum_h (Wv_h @ P_h^T) @ Wp_h; out = X@Wf + b + dwconv2(gelu(dwconv1(X)))

#define NTOK 131072

typedef __attribute__((ext_vector_type(8))) short short8v;
typedef __attribute__((ext_vector_type(4))) float f32x4;

__device__ __forceinline__ uint32_t pk2(float a, float b) {
    return ((__float_as_uint(a) + 0x8000u) >> 16) |
           (((__float_as_uint(b) + 0x8000u) >> 16) << 16);
}
__device__ __forceinline__ float bl(uint32_t w) { return __uint_as_float(w << 16); }
__device__ __forceinline__ float bh(uint32_t w) { return __uint_as_float(w & 0xFFFF0000u); }

// ---------------- K1: Gram via MFMA, per-wave partials (verified r5) -------
__global__ __launch_bounds__(256) void k_gram(const float* __restrict__ x,
                                              float* __restrict__ partial) {
    const int tid = threadIdx.x;
    const int lane = tid & 63;
    const int wave = tid >> 6;
    const int gwave = blockIdx.x * 4 + wave;   // 0..2047
    const int lh = lane >> 4;
    const int lc = lane & 15;
    f32x4 acc[10];
#pragma unroll
    for (int t = 0; t < 10; ++t) acc[t] = (f32x4){0.f, 0.f, 0.f, 0.f};
    const long tokBase = (long)gwave * 64;
#pragma unroll
    for (int s = 0; s < 2; ++s) {
        const long t0 = tokBase + s * 32 + lh * 8;
        float v[4][8];
#pragma unroll
        for (int r = 0; r < 4; ++r) {
            const float* p = x + t0 * 64 + r * 16 + lc;
#pragma unroll
            for (int i = 0; i < 8; ++i) v[r][i] = p[i * 64];
        }
        union { short8v s8; uint32_t u[4]; } fh[4], fl[4];
#pragma unroll
        for (int r = 0; r < 4; ++r) {
#pragma unroll
            for (int w = 0; w < 4; ++w) {
                const float a = v[r][2 * w], b = v[r][2 * w + 1];
                const uint32_t hw = pk2(a, b);
                fh[r].u[w] = hw;
                fl[r].u[w] = pk2(a - bl(hw), b - bh(hw));
            }
        }
#pragma unroll
        for (int td = 0; td < 4; ++td) {
#pragma unroll
            for (int te = td; te < 4; ++te) {
                const int t = td * 4 + te - (td * (td + 1)) / 2;
                acc[t] = __builtin_amdgcn_mfma_f32_16x16x32_bf16(fh[td].s8, fh[te].s8, acc[t], 0, 0, 0);
                acc[t] = __builtin_amdgcn_mfma_f32_16x16x32_bf16(fh[td].s8, fl[te].s8, acc[t], 0, 0, 0);
                acc[t] = __builtin_amdgcn_mfma_f32_16x16x32_bf16(fl[td].s8, fh[te].s8, acc[t], 0, 0, 0);
            }
        }
    }
    float* pb = partial + (size_t)gwave * 2560;
#pragma unroll
    for (int t = 0; t < 10; ++t)
#pragma unroll
        for (int j = 0; j < 4; ++j)
            pb[t * 256 + (lh * 4 + j) * 16 + lc] = acc[t][j];
}

// ---------------- K2: reduce wave-partials -> G -----------------
__global__ __launch_bounds__(256) void k_reduceG(const float* __restrict__ partial,
                                                 float* __restrict__ G) {
    const int entry = (blockIdx.x & 15) * 256 + threadIdx.x;
    const int slice = blockIdx.x >> 4;
    const int d = entry >> 6, e = entry & 63;
    int td = d >> 4, te = e >> 4, r = d & 15, c = e & 15;
    if (td > te) { int t = td; td = te; te = t; t = r; r = c; c = t; }
    const int off = (td * 4 + te - (td * (td + 1)) / 2) * 256 + r * 16 + c;
    const float* p = partial + (size_t)slice * 64 * 2560 + off;
    float s = 0.f;
#pragma unroll 8
    for (int i = 0; i < 64; ++i) s += p[(size_t)i * 2560];
    atomicAdd(&G[entry], s);
}

// ---------------- K3: tiny attention algebra (4 blocks) ----------
__global__ __launch_bounds__(512) void k_attn(const float* __restrict__ G,
                                              const float* __restrict__ w_qkv,
                                              const float* __restrict__ rescale,
                                              const float* __restrict__ w_proj,
                                              float* __restrict__ wf) {
    __shared__ float smem[6 * 4096 + 64 * 65];
    float (*Gs)[64] = (float(*)[64])smem;
    float (*PT)[64] = (float(*)[64])smem;  // alias (Gs dead after P1)
    float (*Bq)[64] = (float(*)[64])(smem + 4096);
    float (*Bk)[64] = (float(*)[64])(smem + 8192);
    float (*Bp)[64] = (float(*)[64])(smem + 12288);
    float (*M1)[64] = (float(*)[64])(smem + 16384);
    float (*M2)[64] = (float(*)[64])(smem + 20480);
    float (*Sb)[65] = (float(*)[65])(smem + 24576);
    __shared__ float qin[64], kin[64];

    const int h = blockIdx.x;
    const int tid = threadIdx.x;
    const int lane = tid & 63;
    const int g = tid >> 6;
    const int p0 = g * 8;

    for (int idx = tid; idx < 4096; idx += 512) {
        const int a = idx >> 6, e = idx & 63;
        Gs[a][e] = G[idx];
        Bq[a][e] = w_qkv[a * 768 + h * 64 + e];
        Bk[a][e] = w_qkv[a * 768 + 256 + h * 64 + e];
        Bp[a][e] = w_proj[(h * 64 + a) * 64 + e];
    }
    __syncthreads();

    {
        float acc[8];
#pragma unroll
        for (int i = 0; i < 8; ++i) acc[i] = 0.f;
        for (int a = 0; a < 64; ++a) {
            const float r = Bq[a][lane];
            const float4 l0 = *(const float4*)&Gs[a][p0];
            const float4 l1 = *(const float4*)&Gs[a][p0 + 4];
            acc[0] += l0.x * r; acc[1] += l0.y * r; acc[2] += l0.z * r; acc[3] += l0.w * r;
            acc[4] += l1.x * r; acc[5] += l1.y * r; acc[6] += l1.z * r; acc[7] += l1.w * r;
        }
#pragma unroll
        for (int i = 0; i < 8; ++i) M1[p0 + i][lane] = acc[i];
    }
    {
        float acc[8];
#pragma unroll
        for (int i = 0; i < 8; ++i) acc[i] = 0.f;
        for (int a = 0; a < 64; ++a) {
            const float r = Bk[a][lane];
            const float4 l0 = *(const float4*)&Gs[a][p0];
            const float4 l1 = *(const float4*)&Gs[a][p0 + 4];
            acc[0] += l0.x * r; acc[1] += l0.y * r; acc[2] += l0.z * r; acc[3] += l0.w * r;
            acc[4] += l1.x * r; acc[5] += l1.y * r; acc[6] += l1.z * r; acc[7] += l1.w * r;
        }
#pragma unroll
        for (int i = 0; i < 8; ++i) M2[p0 + i][lane] = acc[i];
    }
    __syncthreads();

    if (tid < 64) {
        float s = 0.f;
        for (int a = 0; a < 64; ++a) s += Bq[a][tid] * M1[a][tid];
        qin[tid] = 1.f / fmaxf(sqrtf(s), 1e-12f);
    } else if (tid < 128) {
        const int d = tid - 64;
        float s = 0.f;
        for (int a = 0; a < 64; ++a) s += Bk[a][d] * M2[a][d];
        kin[d] = 1.f / fmaxf(sqrtf(s), 1e-12f);
    }
    __syncthreads();

    const float rs = rescale[h];
    {
        float acc[8];
#pragma unroll
        for (int i = 0; i < 8; ++i) acc[i] = 0.f;
        for (int a = 0; a < 64; ++a) {
            const float r = M1[a][lane];
            const float4 l0 = *(const float4*)&Bk[a][p0];
            const float4 l1 = *(const float4*)&Bk[a][p0 + 4];
            acc[0] += l0.x * r; acc[1] += l0.y * r; acc[2] += l0.z * r; acc[3] += l0.w * r;
            acc[4] += l1.x * r; acc[5] += l1.y * r; acc[6] += l1.z * r; acc[7] += l1.w * r;
        }
        const float qv = qin[lane] * rs;
#pragma unroll
        for (int i = 0; i < 8; ++i) Sb[p0 + i][lane] = acc[i] * (kin[p0 + i] * qv);
    }
    for (int idx = tid; idx < 4096; idx += 512) {
        const int a = idx >> 6, e = idx & 63;
        Bq[e][a] = w_qkv[a * 768 + 512 + h * 64 + e];  // WvT[e][a]
    }
    __syncthreads();

    if (tid < 64) {
        const int d = tid;
        float m = -1e30f;
        for (int e = 0; e < 64; ++e) m = fmaxf(m, Sb[d][e]);
        float s = 0.f;
        for (int e = 0; e < 64; ++e) {
            const float pv = expf(Sb[d][e] - m);
            s += pv;
            PT[e][d] = pv;
        }
        const float inv = 1.f / s;
        for (int e = 0; e < 64; ++e) PT[e][d] *= inv;
    }
    __syncthreads();

    {
        float acc[8];
#pragma unroll
        for (int i = 0; i < 8; ++i) acc[i] = 0.f;
        for (int e = 0; e < 64; ++e) {
            const float r = Bq[e][lane];
            const float4 l0 = *(const float4*)&PT[e][p0];
            const float4 l1 = *(const float4*)&PT[e][p0 + 4];
            acc[0] += l0.x * r; acc[1] += l0.y * r; acc[2] += l0.z * r; acc[3] += l0.w * r;
            acc[4] += l1.x * r; acc[5] += l1.y * r; acc[6] += l1.z * r; acc[7] += l1.w * r;
        }
        __syncthreads();
#pragma unroll
        for (int i = 0; i < 8; ++i) M2[p0 + i][lane] = acc[i];
    }
    __syncthreads();

    {
        float acc[8];
#pragma unroll
        for (int i = 0; i < 8; ++i) acc[i] = 0.f;
        for (int d = 0; d < 64; ++d) {
            const float r = Bp[d][lane];
            const float4 l0 = *(const float4*)&M2[d][p0];
            const float4 l1 = *(const float4*)&M2[d][p0 + 4];
            acc[0] += l0.x * r; acc[1] += l0.y * r; acc[2] += l0.z * r; acc[3] += l0.w * r;
            acc[4] += l1.x * r; acc[5] += l1.y * r; acc[6] += l1.z * r; acc[7] += l1.w * r;
        }
#pragma unroll
        for (int i = 0; i < 8; ++i) atomicAdd(&wf[(p0 + i) * 64 + lane], acc[i]);
    }
}

// ---------------- K4: out = X @ Wf + b_proj via split-bf16 MFMA ------------
// 1024 blocks x 256 thr (4 waves); wave handles 2 strips of 16 tokens.
// Frag convention (HW-verified by k_gram): operand lane&15 = output index,
// k = (lane>>4)*8 + j;  D: col=lane&15, row=(lane>>4)*4+reg.
__global__ __launch_bounds__(256) void k_out(const float* __restrict__ x,
                                             const float* __restrict__ wf_g,
                                             const float* __restrict__ b_proj,
                                             float* __restrict__ out) {
    const int tid = threadIdx.x;
    const int lane = tid & 63;
    const int wave = tid >> 6;
    const int lr = lane & 15;   // token-in-strip (A) / out col (B,D)
    const int kg = lane >> 4;   // k-group

    // Preload Wf B-frags (hi+lo) and bias
    union { short8v s8; uint32_t u[4]; } wfh[2][4], wfl[2][4];  // [kstep][ntile]
#pragma unroll
    for (int ks = 0; ks < 2; ++ks)
#pragma unroll
        for (int nt = 0; nt < 4; ++nt)
#pragma unroll
            for (int w = 0; w < 4; ++w) {
                const int k0 = ks * 32 + kg * 8 + 2 * w;
                const float a = wf_g[k0 * 64 + nt * 16 + lr];
                const float b = wf_g[(k0 + 1) * 64 + nt * 16 + lr];
                const uint32_t hw = pk2(a, b);
                wfh[ks][nt].u[w] = hw;
                wfl[ks][nt].u[w] = pk2(a - bl(hw), b - bh(hw));
            }
    float bb[4];
#pragma unroll
    for (int nt = 0; nt < 4; ++nt) bb[nt] = b_proj[nt * 16 + lr];

    const long strip0 = ((long)blockIdx.x * 4 + wave) * 2;
#pragma unroll
    for (int s = 0; s < 2; ++s) {
        const long tok0 = (strip0 + s) * 16;
        union { short8v s8; uint32_t u[4]; } ah[2], al[2];
#pragma unroll
        for (int ks = 0; ks < 2; ++ks) {
            const float* p = x + (tok0 + lr) * 64 + ks * 32 + kg * 8;
            const float4 a0 = *(const float4*)p;
            const float4 a1 = *(const float4*)(p + 4);
            const float va[8] = {a0.x, a0.y, a0.z, a0.w, a1.x, a1.y, a1.z, a1.w};
#pragma unroll
            for (int w = 0; w < 4; ++w) {
                const uint32_t hw = pk2(va[2 * w], va[2 * w + 1]);
                ah[ks].u[w] = hw;
                al[ks].u[w] = pk2(va[2 * w] - bl(hw), va[2 * w + 1] - bh(hw));
            }
        }
        f32x4 acc[4];
#pragma unroll
        for (int nt = 0; nt < 4; ++nt) acc[nt] = (f32x4){0.f, 0.f, 0.f, 0.f};
#pragma unroll
        for (int ks = 0; ks < 2; ++ks)
#pragma unroll
            for (int nt = 0; nt < 4; ++nt) {
                acc[nt] = __builtin_amdgcn_mfma_f32_16x16x32_bf16(ah[ks].s8, wfh[ks][nt].s8, acc[nt], 0, 0, 0);
                acc[nt] = __builtin_amdgcn_mfma_f32_16x16x32_bf16(ah[ks].s8, wfl[ks][nt].s8, acc[nt], 0, 0, 0);
                acc[nt] = __builtin_amdgcn_mfma_f32_16x16x32_bf16(al[ks].s8, wfh[ks][nt].s8, acc[nt], 0, 0, 0);
            }
#pragma unroll
        for (int nt = 0; nt < 4; ++nt)
#pragma unroll
            for (int j = 0; j < 4; ++j)
                out[(tok0 + kg * 4 + j) * 64 + nt * 16 + lr] = acc[nt][j] + bb[nt];
    }
}

// ---------------- K5: fused depthwise conv3d -> gelu -> conv3d, += out -----
// f32 x-columns (no unpack in conv1), bf16 y1. 62KB LDS, full-depth columns.
__global__ __launch_bounds__(256) void k_conv(const float* __restrict__ x,
                                              const float* __restrict__ w1,
                                              const float* __restrict__ w2,
                                              float* __restrict__ out) {
    __shared__ float xt[12][12][8][10];    // 46080B: slot s: s=0 pad, s=1..8 gd=0..7, s=9 pad
    __shared__ uint32_t y1[10][10][8][5];  // 16000B: bf16 pairs, k=0..9 (k=0,9 pad)
    const int tid = threadIdx.x;
    const int b = blockIdx.x;
    const int xcd = b & 7, seq = (b >> 3) & 31, cg = b >> 8;
    const int tile = xcd * 32 + seq;
    const int tw = tile & 15, th = tile >> 4;
    const int h0 = th * 8, w0 = tw * 8;
    const int c = tid & 7;
    const int cglob = cg * 8 + c;

    float wr1[27];
#pragma unroll
    for (int o = 0; o < 27; ++o) wr1[o] = w1[cglob * 27 + o];

    // ---- load x tile -> f32 columns (zero outside image) ----
    for (int e = tid; e < 1152; e += 256) {
        const int sp = e >> 3;
        const int hh = sp / 12;
        const int ww = sp - hh * 12;
        const int gh = h0 + hh - 2, gw = w0 + ww - 2;
        float col[10];
#pragma unroll
        for (int i = 0; i < 10; ++i) col[i] = 0.f;
        if ((unsigned)gh < 128u && (unsigned)gw < 128u) {
            const float* xp = x + ((long)gh * 128 + gw) * 64 + cglob;
#pragma unroll
            for (int gd = 0; gd < 8; ++gd) col[gd + 1] = xp[(long)gd * 1048576];
        }
        float* dst = &xt[hh][ww][e & 7][0];
#pragma unroll
        for (int i = 0; i < 5; ++i) *(float2*)(dst + 2 * i) = make_float2(col[2 * i], col[2 * i + 1]);
    }
    __syncthreads();

    // ---- conv1 + gelu -> y1 (bf16 columns) ----
    for (int e = tid; e < 800; e += 256) {
        const int sp = e >> 3;
        const int hi_ = sp / 10;
        const int wi = sp - hi_ * 10;
        const int ghp = h0 + hi_ - 1, gwp = w0 + wi - 1;
        uint32_t ow_[5];
        if ((unsigned)ghp < 128u && (unsigned)gwp < 128u) {
            float acc[8];
#pragma unroll
            for (int j = 0; j < 8; ++j) acc[j] = 0.f;
#pragma unroll
            for (int oh = 0; oh < 3; ++oh) {
#pragma unroll
                for (int ow = 0; ow < 3; ++ow) {
                    const float* cp = &xt[hi_ + oh][wi + ow][e & 7][0];
                    float xc[10];
#pragma unroll
                    for (int s2 = 0; s2 < 5; ++s2) {
                        const float2 t = *(const float2*)(cp + 2 * s2);
                        xc[2 * s2] = t.x; xc[2 * s2 + 1] = t.y;
                    }
                    const float wg0 = wr1[oh * 3 + ow];
                    const float wg1 = wr1[9 + oh * 3 + ow];
                    const float wg2 = wr1[18 + oh * 3 + ow];
#pragma unroll
                    for (int j = 0; j < 8; ++j)
                        acc[j] += wg0 * xc[j] + wg1 * xc[j + 1] + wg2 * xc[j + 2];
                }
            }
            float gl[8];
#pragma unroll
            for (int j = 0; j < 8; ++j)
                gl[j] = 0.5f * acc[j] * (1.f + erff(acc[j] * 0.70710678118654752f));
            ow_[0] = pk2(0.f, gl[0]);
            ow_[1] = pk2(gl[1], gl[2]);
            ow_[2] = pk2(gl[3], gl[4]);
            ow_[3] = pk2(gl[5], gl[6]);
            ow_[4] = pk2(gl[7], 0.f);
        } else {
#pragma unroll
            for (int i = 0; i < 5; ++i) ow_[i] = 0u;
        }
        uint32_t* dst = &y1[hi_][wi][e & 7][0];
#pragma unroll
        for (int i = 0; i < 5; ++i) dst[i] = ow_[i];
    }

    float wr2[27];
#pragma unroll
    for (int o = 0; o < 27; ++o) wr2[o] = w2[cglob * 27 + o];
    __syncthreads();

    // ---- conv2 -> out (RMW add) ----
    for (int e = tid; e < 512; e += 256) {
        const int sp = e >> 3;
        const int ho = sp >> 3, wo = sp & 7;
        float a2[8];
#pragma unroll
        for (int j = 0; j < 8; ++j) a2[j] = 0.f;
#pragma unroll
        for (int oh = 0; oh < 3; ++oh) {
#pragma unroll
            for (int ow = 0; ow < 3; ++ow) {
                const uint32_t* cp = &y1[ho + oh][wo + ow][e & 7][0];
                float yc[10];
#pragma unroll
                for (int wdx = 0; wdx < 5; ++wdx) {
                    const uint32_t wv = cp[wdx];
                    yc[2 * wdx] = bl(wv);
                    yc[2 * wdx + 1] = bh(wv);
                }
                const float wg0 = wr2[oh * 3 + ow];
                const float wg1 = wr2[9 + oh * 3 + ow];
                const float wg2 = wr2[18 + oh * 3 + ow];
#pragma unroll
                for (int j = 0; j < 8; ++j)
                    a2[j] += wg0 * yc[j] + wg1 * yc[j + 1] + wg2 * yc[j + 2];
            }
        }
        const int gh = h0 + ho, gw = w0 + wo;
        float* op = out + ((long)gh * 128 + gw) * 64 + cglob;
#pragma unroll
        for (int j = 0; j < 8; ++j) op[(long)j * 1048576] += a2[j];
    }
}

extern "C" void kernel_launch(void* const* d_in, const int* in_sizes, int n_in,
                              void* d_out, int out_size, void* d_ws, size_t ws_size,
                              hipStream_t stream) {
    const float* x       = (const float*)d_in[0];
    const float* w_qkv   = (const float*)d_in[1];
    const float* rescale = (const float*)d_in[2];
    const float* w_proj  = (const float*)d_in[3];
    const float* b_proj  = (const float*)d_in[4];
    const float* w_pe1   = (const float*)d_in[5];
    const float* w_pe2   = (const float*)d_in[6];
    float* out = (float*)d_out;

    float* G  = (float*)d_ws;   // 4096 floats (atomic)
    float* wf = G + 4096;       // 4096 floats (atomic)
    float* partial = out;       // 2048 x 2560 f32 = 21MB, overwritten by k_out

    hipMemsetAsync(G, 0, 8192 * sizeof(float), stream);
    k_gram<<<512, 256, 0, stream>>>(x, partial);
    k_reduceG<<<512, 256, 0, stream>>>(partial, G);
    k_attn<<<4, 512, 0, stream>>>(G, w_qkv, rescale, w_proj, wf);
    k_out<<<1024, 256, 0, stream>>>(x, wf, b_proj, out);
    k_conv<<<2048, 256, 0, stream>>>(x, w_pe1, w_pe2, out);
}

// Round 8
// 188.428 us; speedup vs baseline: 1.7383x; 1.0997x over previous
//
#include <hip/hip_runtime.h>
#include <hip/hip_bf16.h>
#include <math.h>

// Problem: b=1, D=8, H=128, W=128, C=64; N = 131072 tokens.
// Factored algebra:
//   G = X^T X (64x64, split-bf16 MFMA); channel norms + softmax on G-derived 64x64;
//   W_final = sum_h (Wv_h @ P_h^T) @ Wp_h; out = X@Wf + b + dwconv2(gelu(dwconv1(X)))

#define NTOK 131072

typedef __attribute__((ext_vector_type(8))) short short8v;
typedef __attribute__((ext_vector_type(4))) float f32x4;

__device__ __forceinline__ uint32_t pk2(float a, float b) {
    return ((__float_as_uint(a) + 0x8000u) >> 16) |
           (((__float_as_uint(b) + 0x8000u) >> 16) << 16);
}
__device__ __forceinline__ uint16_t pk1(float a) {
    return (uint16_t)((__float_as_uint(a) + 0x8000u) >> 16);
}
__device__ __forceinline__ float bl(uint32_t w) { return __uint_as_float(w << 16); }
__device__ __forceinline__ float bh(uint32_t w) { return __uint_as_float(w & 0xFFFF0000u); }

// ---------------- K1: Gram via MFMA, per-BLOCK partials (in-block reduce) ---
// 512 blocks x 4 waves; wave owns 64 tokens. Waves 1-3 dump acc to LDS; wave 0
// sums -> partial[block][2560]. Block 0 also zeroes G/wf (consumed only by
// later kernels; stream order guarantees visibility).
__global__ __launch_bounds__(256) void k_gram(const float* __restrict__ x,
                                              float* __restrict__ partial,
                                              float* __restrict__ Gwf) {
    __shared__ float lred[3][2560];
    const int tid = threadIdx.x;
    const int lane = tid & 63;
    const int wave = tid >> 6;
    const int lh = lane >> 4;
    const int lc = lane & 15;
    if (blockIdx.x == 0) {
        for (int i = tid; i < 8192; i += 256) Gwf[i] = 0.f;
    }
    f32x4 acc[10];
#pragma unroll
    for (int t = 0; t < 10; ++t) acc[t] = (f32x4){0.f, 0.f, 0.f, 0.f};
    const long tokBase = ((long)blockIdx.x * 4 + wave) * 64;
#pragma unroll
    for (int s = 0; s < 2; ++s) {
        const long t0 = tokBase + s * 32 + lh * 8;
        float v[4][8];
#pragma unroll
        for (int r = 0; r < 4; ++r) {
            const float* p = x + t0 * 64 + r * 16 + lc;
#pragma unroll
            for (int i = 0; i < 8; ++i) v[r][i] = p[i * 64];
        }
        union { short8v s8; uint32_t u[4]; } fh[4], fl[4];
#pragma unroll
        for (int r = 0; r < 4; ++r) {
#pragma unroll
            for (int w = 0; w < 4; ++w) {
                const float a = v[r][2 * w], b = v[r][2 * w + 1];
                const uint32_t hw = pk2(a, b);
                fh[r].u[w] = hw;
                fl[r].u[w] = pk2(a - bl(hw), b - bh(hw));
            }
        }
#pragma unroll
        for (int td = 0; td < 4; ++td) {
#pragma unroll
            for (int te = td; te < 4; ++te) {
                const int t = td * 4 + te - (td * (td + 1)) / 2;
                acc[t] = __builtin_amdgcn_mfma_f32_16x16x32_bf16(fh[td].s8, fh[te].s8, acc[t], 0, 0, 0);
                acc[t] = __builtin_amdgcn_mfma_f32_16x16x32_bf16(fh[td].s8, fl[te].s8, acc[t], 0, 0, 0);
                acc[t] = __builtin_amdgcn_mfma_f32_16x16x32_bf16(fl[td].s8, fh[te].s8, acc[t], 0, 0, 0);
            }
        }
    }
    // C/D layout: col = lane&15, row = (lane>>4)*4 + reg
    if (wave != 0) {
#pragma unroll
        for (int t = 0; t < 10; ++t)
#pragma unroll
            for (int j = 0; j < 4; ++j)
                lred[wave - 1][t * 256 + (lh * 4 + j) * 16 + lc] = acc[t][j];
    }
    __syncthreads();
    if (wave == 0) {
        float* pb = partial + (size_t)blockIdx.x * 2560;
#pragma unroll
        for (int t = 0; t < 10; ++t)
#pragma unroll
            for (int j = 0; j < 4; ++j) {
                const int e = t * 256 + (lh * 4 + j) * 16 + lc;
                pb[e] = acc[t][j] + lred[0][e] + lred[1][e] + lred[2][e];
            }
    }
}

// ---------------- K2: reduce 512 block-partials -> G -----------------
// grid 128: (slice 0..7) x (eblk 0..15); 8 atomics per entry.
__global__ __launch_bounds__(256) void k_reduceG(const float* __restrict__ partial,
                                                 float* __restrict__ G) {
    const int entry = (blockIdx.x & 15) * 256 + threadIdx.x;
    const int slice = blockIdx.x >> 4;
    const int d = entry >> 6, e = entry & 63;
    int td = d >> 4, te = e >> 4, r = d & 15, c = e & 15;
    if (td > te) { int t = td; td = te; te = t; t = r; r = c; c = t; }
    const int off = (td * 4 + te - (td * (td + 1)) / 2) * 256 + r * 16 + c;
    const float* p = partial + (size_t)slice * 64 * 2560 + off;
    float s = 0.f;
#pragma unroll 8
    for (int i = 0; i < 64; ++i) s += p[(size_t)i * 2560];
    atomicAdd(&G[entry], s);
}

// ---------------- K3: tiny attention algebra (4 blocks) ----------
__global__ __launch_bounds__(512) void k_attn(const float* __restrict__ G,
                                              const float* __restrict__ w_qkv,
                                              const float* __restrict__ rescale,
                                              const float* __restrict__ w_proj,
                                              float* __restrict__ wf) {
    __shared__ float smem[6 * 4096 + 64 * 65];
    float (*Gs)[64] = (float(*)[64])smem;
    float (*PT)[64] = (float(*)[64])smem;  // alias (Gs dead after P1)
    float (*Bq)[64] = (float(*)[64])(smem + 4096);
    float (*Bk)[64] = (float(*)[64])(smem + 8192);
    float (*Bp)[64] = (float(*)[64])(smem + 12288);
    float (*M1)[64] = (float(*)[64])(smem + 16384);
    float (*M2)[64] = (float(*)[64])(smem + 20480);
    float (*Sb)[65] = (float(*)[65])(smem + 24576);
    __shared__ float qin[64], kin[64];

    const int h = blockIdx.x;
    const int tid = threadIdx.x;
    const int lane = tid & 63;
    const int g = tid >> 6;
    const int p0 = g * 8;

    for (int idx = tid; idx < 4096; idx += 512) {
        const int a = idx >> 6, e = idx & 63;
        Gs[a][e] = G[idx];
        Bq[a][e] = w_qkv[a * 768 + h * 64 + e];
        Bk[a][e] = w_qkv[a * 768 + 256 + h * 64 + e];
        Bp[a][e] = w_proj[(h * 64 + a) * 64 + e];
    }
    __syncthreads();

    {
        float acc[8];
#pragma unroll
        for (int i = 0; i < 8; ++i) acc[i] = 0.f;
        for (int a = 0; a < 64; ++a) {
            const float r = Bq[a][lane];
            const float4 l0 = *(const float4*)&Gs[a][p0];
            const float4 l1 = *(const float4*)&Gs[a][p0 + 4];
            acc[0] += l0.x * r; acc[1] += l0.y * r; acc[2] += l0.z * r; acc[3] += l0.w * r;
            acc[4] += l1.x * r; acc[5] += l1.y * r; acc[6] += l1.z * r; acc[7] += l1.w * r;
        }
#pragma unroll
        for (int i = 0; i < 8; ++i) M1[p0 + i][lane] = acc[i];
    }
    {
        float acc[8];
#pragma unroll
        for (int i = 0; i < 8; ++i) acc[i] = 0.f;
        for (int a = 0; a < 64; ++a) {
            const float r = Bk[a][lane];
            const float4 l0 = *(const float4*)&Gs[a][p0];
            const float4 l1 = *(const float4*)&Gs[a][p0 + 4];
            acc[0] += l0.x * r; acc[1] += l0.y * r; acc[2] += l0.z * r; acc[3] += l0.w * r;
            acc[4] += l1.x * r; acc[5] += l1.y * r; acc[6] += l1.z * r; acc[7] += l1.w * r;
        }
#pragma unroll
        for (int i = 0; i < 8; ++i) M2[p0 + i][lane] = acc[i];
    }
    __syncthreads();

    if (tid < 64) {
        float s = 0.f;
        for (int a = 0; a < 64; ++a) s += Bq[a][tid] * M1[a][tid];
        qin[tid] = 1.f / fmaxf(sqrtf(s), 1e-12f);
    } else if (tid < 128) {
        const int d = tid - 64;
        float s = 0.f;
        for (int a = 0; a < 64; ++a) s += Bk[a][d] * M2[a][d];
        kin[d] = 1.f / fmaxf(sqrtf(s), 1e-12f);
    }
    __syncthreads();

    const float rs = rescale[h];
    {
        float acc[8];
#pragma unroll
        for (int i = 0; i < 8; ++i) acc[i] = 0.f;
        for (int a = 0; a < 64; ++a) {
            const float r = M1[a][lane];
            const float4 l0 = *(const float4*)&Bk[a][p0];
            const float4 l1 = *(const float4*)&Bk[a][p0 + 4];
            acc[0] += l0.x * r; acc[1] += l0.y * r; acc[2] += l0.z * r; acc[3] += l0.w * r;
            acc[4] += l1.x * r; acc[5] += l1.y * r; acc[6] += l1.z * r; acc[7] += l1.w * r;
        }
        const float qv = qin[lane] * rs;
#pragma unroll
        for (int i = 0; i < 8; ++i) Sb[p0 + i][lane] = acc[i] * (kin[p0 + i] * qv);
    }
    for (int idx = tid; idx < 4096; idx += 512) {
        const int a = idx >> 6, e = idx & 63;
        Bq[e][a] = w_qkv[a * 768 + 512 + h * 64 + e];  // WvT[e][a]
    }
    __syncthreads();

    if (tid < 64) {
        const int d = tid;
        float m = -1e30f;
        for (int e = 0; e < 64; ++e) m = fmaxf(m, Sb[d][e]);
        float s = 0.f;
        for (int e = 0; e < 64; ++e) {
            const float pv = expf(Sb[d][e] - m);
            s += pv;
            PT[e][d] = pv;
        }
        const float inv = 1.f / s;
        for (int e = 0; e < 64; ++e) PT[e][d] *= inv;
    }
    __syncthreads();

    {
        float acc[8];
#pragma unroll
        for (int i = 0; i < 8; ++i) acc[i] = 0.f;
        for (int e = 0; e < 64; ++e) {
            const float r = Bq[e][lane];
            const float4 l0 = *(const float4*)&PT[e][p0];
            const float4 l1 = *(const float4*)&PT[e][p0 + 4];
            acc[0] += l0.x * r; acc[1] += l0.y * r; acc[2] += l0.z * r; acc[3] += l0.w * r;
            acc[4] += l1.x * r; acc[5] += l1.y * r; acc[6] += l1.z * r; acc[7] += l1.w * r;
        }
        __syncthreads();
#pragma unroll
        for (int i = 0; i < 8; ++i) M2[p0 + i][lane] = acc[i];
    }
    __syncthreads();

    {
        float acc[8];
#pragma unroll
        for (int i = 0; i < 8; ++i) acc[i] = 0.f;
        for (int d = 0; d < 64; ++d) {
            const float r = Bp[d][lane];
            const float4 l0 = *(const float4*)&M2[d][p0];
            const float4 l1 = *(const float4*)&M2[d][p0 + 4];
            acc[0] += l0.x * r; acc[1] += l0.y * r; acc[2] += l0.z * r; acc[3] += l0.w * r;
            acc[4] += l1.x * r; acc[5] += l1.y * r; acc[6] += l1.z * r; acc[7] += l1.w * r;
        }
#pragma unroll
        for (int i = 0; i < 8; ++i) atomicAdd(&wf[(p0 + i) * 64 + lane], acc[i]);
    }
}

// ---------------- K5: fused depthwise conv3d -> gelu -> conv3d ------------
// bf16 columns; float4 staging (4 ch/load). WS=1: write conv result bf16 to
// scratch (no out access). WS=0: legacy RMW add into out.
template <int WS>
__global__ __launch_bounds__(256) void k_conv(const float* __restrict__ x,
                                              const float* __restrict__ w1,
                                              const float* __restrict__ w2,
                                              float* __restrict__ out,
                                              uint16_t* __restrict__ cws) {
    __shared__ uint32_t xt[12][12][5][8];  // 23040B: slot-major, ch-minor bf16 pairs
    __shared__ uint32_t y1[10][10][8][5];  // 16000B: per-ch columns, k=0..9 (0,9 pad)
    const int tid = threadIdx.x;
    const int b = blockIdx.x;
    const int xcd = b & 7, seq = (b >> 3) & 31, cg = b >> 8;
    const int tile = xcd * 32 + seq;
    const int tw = tile & 15, th = tile >> 4;
    const int h0 = th * 8, w0 = tw * 8;
    const int c = tid & 7;
    const int cglob = cg * 8 + c;

    float wr1[27];
#pragma unroll
    for (int o = 0; o < 27; ++o) wr1[o] = w1[cglob * 27 + o];

    // ---- stage x -> bf16 columns via float4 (4ch) loads ----
    // 288 tasks: cq = e&1 (ch quad), sp = e>>1 over 12x12
    for (int e = tid; e < 288; e += 256) {
        const int cq = e & 1;
        const int sp = e >> 1;
        const int hh = sp / 12;
        const int ww = sp - hh * 12;
        const int gh = h0 + hh - 2, gw = w0 + ww - 2;
        uint32_t wv[5][4];
#pragma unroll
        for (int s = 0; s < 5; ++s)
#pragma unroll
            for (int cc = 0; cc < 4; ++cc) wv[s][cc] = 0u;
        if ((unsigned)gh < 128u && (unsigned)gw < 128u) {
            float a[8][4];
#pragma unroll
            for (int gd = 0; gd < 8; ++gd) {
                const float4 q = *(const float4*)(x + (((long)gd * 16384 + gh * 128 + gw)) * 64 + cg * 8 + cq * 4);
                a[gd][0] = q.x; a[gd][1] = q.y; a[gd][2] = q.z; a[gd][3] = q.w;
            }
#pragma unroll
            for (int cc = 0; cc < 4; ++cc) {
                wv[0][cc] = pk2(0.f, a[0][cc]);
                wv[1][cc] = pk2(a[1][cc], a[2][cc]);
                wv[2][cc] = pk2(a[3][cc], a[4][cc]);
                wv[3][cc] = pk2(a[5][cc], a[6][cc]);
                wv[4][cc] = pk2(a[7][cc], 0.f);
            }
        }
#pragma unroll
        for (int s = 0; s < 5; ++s)
            *(uint4*)&xt[hh][ww][s][cq * 4] = make_uint4(wv[s][0], wv[s][1], wv[s][2], wv[s][3]);
    }
    __syncthreads();

    // ---- conv1 + gelu -> y1 ----
    for (int e = tid; e < 800; e += 256) {
        const int sp = e >> 3;
        const int hi_ = sp / 10;
        const int wi = sp - hi_ * 10;
        const int ghp = h0 + hi_ - 1, gwp = w0 + wi - 1;
        uint32_t ow_[5];
        if ((unsigned)ghp < 128u && (unsigned)gwp < 128u) {
            float acc[8];
#pragma unroll
            for (int j = 0; j < 8; ++j) acc[j] = 0.f;
#pragma unroll
            for (int oh = 0; oh < 3; ++oh) {
#pragma unroll
                for (int ow = 0; ow < 3; ++ow) {
                    const uint32_t* cp = &xt[hi_ + oh][wi + ow][0][e & 7];
                    float xc[11];  // xc[m] = x at gd = m-2 (m=1..10)
#pragma unroll
                    for (int wdx = 0; wdx < 5; ++wdx) {
                        const uint32_t wv = cp[wdx * 8];
                        xc[2 * wdx + 1] = bl(wv);
                        xc[2 * wdx + 2] = bh(wv);
                    }
                    const float wg0 = wr1[oh * 3 + ow];
                    const float wg1 = wr1[9 + oh * 3 + ow];
                    const float wg2 = wr1[18 + oh * 3 + ow];
#pragma unroll
                    for (int j = 0; j < 8; ++j)
                        acc[j] += wg0 * xc[j + 1] + wg1 * xc[j + 2] + wg2 * xc[j + 3];
                }
            }
            float gl[8];
#pragma unroll
            for (int j = 0; j < 8; ++j)
                gl[j] = 0.5f * acc[j] * (1.f + erff(acc[j] * 0.70710678118654752f));
            ow_[0] = pk2(0.f, gl[0]);
            ow_[1] = pk2(gl[1], gl[2]);
            ow_[2] = pk2(gl[3], gl[4]);
            ow_[3] = pk2(gl[5], gl[6]);
            ow_[4] = pk2(gl[7], 0.f);
        } else {
#pragma unroll
            for (int i = 0; i < 5; ++i) ow_[i] = 0u;
        }
        uint32_t* dst = &y1[hi_][wi][e & 7][0];
#pragma unroll
        for (int i = 0; i < 5; ++i) dst[i] = ow_[i];
    }

    float wr2[27];
#pragma unroll
    for (int o = 0; o < 27; ++o) wr2[o] = w2[cglob * 27 + o];
    __syncthreads();

    // ---- conv2 -> scratch (WS) or RMW out ----
    for (int e = tid; e < 512; e += 256) {
        const int sp = e >> 3;
        const int ho = sp >> 3, wo = sp & 7;
        float a2[8];
#pragma unroll
        for (int j = 0; j < 8; ++j) a2[j] = 0.f;
#pragma unroll
        for (int oh = 0; oh < 3; ++oh) {
#pragma unroll
            for (int ow = 0; ow < 3; ++ow) {
                const uint32_t* cp = &y1[ho + oh][wo + ow][e & 7][0];
                float yc[10];
#pragma unroll
                for (int wdx = 0; wdx < 5; ++wdx) {
                    const uint32_t wv = cp[wdx];
                    yc[2 * wdx] = bl(wv);
                    yc[2 * wdx + 1] = bh(wv);
                }
                const float wg0 = wr2[oh * 3 + ow];
                const float wg1 = wr2[9 + oh * 3 + ow];
                const float wg2 = wr2[18 + oh * 3 + ow];
#pragma unroll
                for (int j = 0; j < 8; ++j)
                    a2[j] += wg0 * yc[j] + wg1 * yc[j + 1] + wg2 * yc[j + 2];
            }
        }
        const int gh = h0 + ho, gw = w0 + wo;
        if (WS) {
#pragma unroll
            for (int j = 0; j < 8; ++j)
                cws[(((long)j * 16384 + gh * 128 + gw)) * 64 + cglob] = pk1(a2[j]);
        } else {
            float* op = out + ((long)gh * 128 + gw) * 64 + cglob;
#pragma unroll
            for (int j = 0; j < 8; ++j) op[(long)j * 1048576] += a2[j];
        }
    }
}

// ---------------- K4: out = X @ Wf + b_proj (+ conv scratch) --------------
template <int WS>
__global__ __launch_bounds__(256) void k_out(const float* __restrict__ x,
                                             const float* __restrict__ wf_g,
                                             const float* __restrict__ b_proj,
                                             const uint16_t* __restrict__ cws,
                                             float* __restrict__ out) {
    const int tid = threadIdx.x;
    const int lane = tid & 63;
    const int wave = tid >> 6;
    const int lr = lane & 15;
    const int kg = lane >> 4;

    union { short8v s8; uint32_t u[4]; } wfh[2][4], wfl[2][4];
#pragma unroll
    for (int ks = 0; ks < 2; ++ks)
#pragma unroll
        for (int nt = 0; nt < 4; ++nt)
#pragma unroll
            for (int w = 0; w < 4; ++w) {
                const int k0 = ks * 32 + kg * 8 + 2 * w;
                const float a = wf_g[k0 * 64 + nt * 16 + lr];
                const float b = wf_g[(k0 + 1) * 64 + nt * 16 + lr];
                const uint32_t hw = pk2(a, b);
                wfh[ks][nt].u[w] = hw;
                wfl[ks][nt].u[w] = pk2(a - bl(hw), b - bh(hw));
            }
    float bb[4];
#pragma unroll
    for (int nt = 0; nt < 4; ++nt) bb[nt] = b_proj[nt * 16 + lr];

    const long strip0 = ((long)blockIdx.x * 4 + wave) * 2;
#pragma unroll
    for (int s = 0; s < 2; ++s) {
        const long tok0 = (strip0 + s) * 16;
        union { short8v s8; uint32_t u[4]; } ah[2], al[2];
#pragma unroll
        for (int ks = 0; ks < 2; ++ks) {
            const float* p = x + (tok0 + lr) * 64 + ks * 32 + kg * 8;
            const float4 a0 = *(const float4*)p;
            const float4 a1 = *(const float4*)(p + 4);
            const float va[8] = {a0.x, a0.y, a0.z, a0.w, a1.x, a1.y, a1.z, a1.w};
#pragma unroll
            for (int w = 0; w < 4; ++w) {
                const uint32_t hw = pk2(va[2 * w], va[2 * w + 1]);
                ah[ks].u[w] = hw;
                al[ks].u[w] = pk2(va[2 * w] - bl(hw), va[2 * w + 1] - bh(hw));
            }
        }
        f32x4 acc[4];
#pragma unroll
        for (int nt = 0; nt < 4; ++nt) acc[nt] = (f32x4){0.f, 0.f, 0.f, 0.f};
#pragma unroll
        for (int ks = 0; ks < 2; ++ks)
#pragma unroll
            for (int nt = 0; nt < 4; ++nt) {
                acc[nt] = __builtin_amdgcn_mfma_f32_16x16x32_bf16(ah[ks].s8, wfh[ks][nt].s8, acc[nt], 0, 0, 0);
                acc[nt] = __builtin_amdgcn_mfma_f32_16x16x32_bf16(ah[ks].s8, wfl[ks][nt].s8, acc[nt], 0, 0, 0);
                acc[nt] = __builtin_amdgcn_mfma_f32_16x16x32_bf16(al[ks].s8, wfh[ks][nt].s8, acc[nt], 0, 0, 0);
            }
#pragma unroll
        for (int nt = 0; nt < 4; ++nt)
#pragma unroll
            for (int j = 0; j < 4; ++j) {
                const long idx = (tok0 + kg * 4 + j) * 64 + nt * 16 + lr;
                float v = acc[nt][j] + bb[nt];
                if (WS) v += __uint_as_float(((uint32_t)cws[idx]) << 16);
                out[idx] = v;
            }
    }
}

extern "C" void kernel_launch(void* const* d_in, const int* in_sizes, int n_in,
                              void* d_out, int out_size, void* d_ws, size_t ws_size,
                              hipStream_t stream) {
    const float* x       = (const float*)d_in[0];
    const float* w_qkv   = (const float*)d_in[1];
    const float* rescale = (const float*)d_in[2];
    const float* w_proj  = (const float*)d_in[3];
    const float* b_proj  = (const float*)d_in[4];
    const float* w_pe1   = (const float*)d_in[5];
    const float* w_pe2   = (const float*)d_in[6];
    float* out = (float*)d_out;

    char* wsb = (char*)d_ws;
    float* G  = (float*)wsb;                    // 4096 floats (atomic)
    float* wf = G + 4096;                       // 4096 floats (atomic)
    uint16_t* cws = (uint16_t*)(wsb + 32768);   // conv result bf16, 16.78MB
    float* partial = out;                       // 512 x 2560 f32 = 5.2MB, in d_out

    const bool ws_ok = ws_size >= (size_t)32768 + (size_t)NTOK * 64 * 2;

    k_gram<<<512, 256, 0, stream>>>(x, partial, G);
    k_reduceG<<<128, 256, 0, stream>>>(partial, G);
    k_attn<<<4, 512, 0, stream>>>(G, w_qkv, rescale, w_proj, wf);
    if (ws_ok) {
        k_conv<1><<<2048, 256, 0, stream>>>(x, w_pe1, w_pe2, nullptr, cws);
        k_out<1><<<1024, 256, 0, stream>>>(x, wf, b_proj, cws, out);
    } else {
        k_out<0><<<1024, 256, 0, stream>>>(x, wf, b_proj, nullptr, out);
        k_conv<0><<<2048, 256, 0, stream>>>(x, w_pe1, w_pe2, out, nullptr);
    }
}